// Round 5
// baseline (6281.910 us; speedup 1.0000x reference)
//
#include <hip/hip_runtime.h>
#include <math.h>

// T=64, B=128, H=256, C=256, K=8, L=3.
// Structure: 2 blocks per sample (unit-half split), 256 blocks, 512 threads.
// Lineage: R4 (passing, 4277us) = gemm8 (all-8-rows x 64-k split-K, W read
// once per block) + 3-round static XOR-tree reduction + R1 proj (verbatim).
// THIS ROUND (block-local only, sync protocol untouched):
// 1) L2 W-prefetch in dead time: R4's FETCH grew to 1.4GB/dispatch (~86KB/
//    block/step HBM misses: per-XCD W set ~3.6MB sits at the 4MB L2 edge and
//    single-touch streaming lets ~3% evict between steps; 900cy misses defeat
//    the 2-stage VGPR prefetch). After posting the phase-0 flag, waves 1-7
//    stream-touch all 5 LSTM W regions (80 loads/thread, sum + asm sink so
//    DCE can't drop them) while tid0 polls the partner; the poll barrier
//    absorbs the vmcnt drain -> misses prefilled off the critical path.
//    Same for WpT (4 loads) during the phase-3 wait.
// 2) Wave-parallel top-8: wave wv == beam-row wv; in-wave 8-round top-8 of
//    its 256 logits (no barriers), then wave 0 merges the 64 candidates
//    in-wave. Replaces 16 block barriers + 8 serial-tid0 scans with 2
//    barriers. Tie-break (val, lowest-idx) preserved; both blocks compute
//    bit-identical selections from identical jnt contents.
// Pair-sync: relaxed agent-scope atomics + monotonic flags (no acquire/release
// so L2 weight residency survives); writer: data -> __syncthreads (vmcnt
// drain) -> tid0 posts flag; reader: tid0 polls -> barrier -> loads. Flags
// zeroed by k_prep each launch (graph-replay safe).
static constexpr size_t O_EMBW  = 0;         // [256 cls][1024 (u*4+g)]  emb@Wih0^T + b0
static constexpr size_t O_WPT   = 262144;    // [256 k][256 c]
static constexpr size_t O_WIHT  = 327680;    // [3][256 k][1024 (u*4+g)]
static constexpr size_t O_WHHT  = 1114112;   // [3][256 k][1024 (u*4+g)]
static constexpr size_t O_BIASC = 1900544;   // [3][256 u][4 g]  bih+bhh
static constexpr size_t O_XCHG  = 1903616;   // [128 smp][2 half][4 phase][1024] floats
static constexpr size_t O_FLAGS = 2952192;   // 1024 uint32: [smp][4 phase][2 half]
// total 2953216 floats ≈ 11.8 MB

typedef float f2 __attribute__((ext_vector_type(2)));
__device__ __forceinline__ f2 fma2(f2 a, f2 b, f2 c){ return __builtin_elementwise_fma(a,b,c); }
__device__ __forceinline__ float sigf(float x){ return 1.0f/(1.0f + expf(-x)); }

__device__ __forceinline__ void astoref(float* p, float v){
  __hip_atomic_store(p, v, __ATOMIC_RELAXED, __HIP_MEMORY_SCOPE_AGENT);
}
__device__ __forceinline__ float aloadf(const float* p){
  return __hip_atomic_load((float*)p, __ATOMIC_RELAXED, __HIP_MEMORY_SCOPE_AGENT);
}

// ---------------- one-time prep: transposes + combined biases + flag reset ----
__global__ __launch_bounds__(256) void k_prep(
    const float* __restrict__ Wih, const float* __restrict__ Whh,
    const float* __restrict__ Wp,  const float* __restrict__ bih,
    const float* __restrict__ bhh,
    float* __restrict__ wihT, float* __restrict__ whhT,
    float* __restrict__ WpT, float* __restrict__ biasC,
    float* __restrict__ flagsF)
{
  const int NT = 786432;
  const int TOTAL = 2*NT + 65536 + 3072 + 1024;
  int stride = gridDim.x * blockDim.x;
  for (int i = blockIdx.x*blockDim.x + threadIdx.x; i < TOTAL; i += stride){
    if (i < NT){
      int l = i / 262144, r = i % 262144;      // r = row*256 + k
      int row = r >> 8, k = r & 255;
      int g = row >> 8, uu = row & 255;
      wihT[(size_t)l*262144 + (k<<10) + (uu<<2) + g] = Wih[i];
    } else if (i < 2*NT){
      int j = i - NT;
      int l = j / 262144, r = j % 262144;
      int row = r >> 8, k = r & 255;
      int g = row >> 8, uu = row & 255;
      whhT[(size_t)l*262144 + (k<<10) + (uu<<2) + g] = Whh[j];
    } else if (i < 2*NT + 65536){
      int j = i - 2*NT; int c = j >> 8, k = j & 255;
      WpT[(k<<8) + c] = Wp[j];
    } else if (i < 2*NT + 65536 + 3072){
      int j = i - 2*NT - 65536;          // [3][256][4]
      int l = j >> 10; int cg = j & 1023, uu = cg >> 2, g = cg & 3;
      biasC[j] = bih[l*1024 + g*256 + uu] + bhh[l*1024 + g*256 + uu];
    } else {
      flagsF[i - (2*NT + 65536 + 3072)] = 0.0f;   // zero sync flags every launch
    }
  }
}

// ------------- one-time: embW[cls][u*4+g] = emb@Wih0^T + bih0 + bhh0 ---------
__global__ __launch_bounds__(256) void k_embW(
    const float* __restrict__ emb, const float* __restrict__ wih0T,
    const float* __restrict__ bih, const float* __restrict__ bhh,
    float* __restrict__ embW)
{
  const int cls = blockIdx.x, uu = threadIdx.x;
  const float* er = emb + cls*256;
  float a0=0.f,a1=0.f,a2=0.f,a3=0.f;
  for (int k=0;k<256;k++){
    float ev = er[k];
    float4 w = *(const float4*)&wih0T[k*1024 + uu*4];
    a0 = fmaf(ev, w.x, a0); a1 = fmaf(ev, w.y, a1);
    a2 = fmaf(ev, w.z, a2); a3 = fmaf(ev, w.w, a3);
  }
  a0 += bih[uu]       + bhh[uu];
  a1 += bih[256+uu]   + bhh[256+uu];
  a2 += bih[512+uu]   + bhh[512+uu];
  a3 += bih[768+uu]   + bhh[768+uu];
  *(float4*)&embW[cls*1024 + uu*4] = make_float4(a0,a1,a2,a3);
}

// ---------------- decode: 2 blocks = 1 sample, 512 threads each --------------
__global__
__attribute__((amdgpu_flat_work_group_size(512,512)))
void k_decode(
    const float* __restrict__ x,      // [64][128][256]
    const float* __restrict__ WpT,    // [256 k][256 c]
    const float* __restrict__ wihT,   // [3][256 k][1024]
    const float* __restrict__ whhT,   // [3][256 k][1024]
    const float* __restrict__ biasC,  // [3][256 u][4 g]
    const float* __restrict__ embW,   // [256 cls][1024]
    const float* __restrict__ bp,     // [256]
    float* __restrict__ xchg,         // [128][2][4][1024]
    unsigned* __restrict__ flags,     // [128][4][2]
    float* __restrict__ out)
{
  __shared__ float hS[3*2048];   // h[l][row][unit 0..255] FULL width   24 KB
  __shared__ float cS[1024];     // staged c_old[row][own-unit 0..127]   4 KB
  __shared__ float st[2048];     // state[row][unit] FULL width          8 KB
  __shared__ float jnt[6144];    // logits / reduction slots (512x12)   24 KB
  __shared__ float pfx[8];
  __shared__ float cvS[64]; __shared__ int ciS[64];   // top-8 candidates
  __shared__ float sVal[8]; __shared__ int sPrev[8], sCls[8];
  __shared__ short prevH[512], clsH[512];

  const int tid  = threadIdx.x;
  const int bid  = blockIdx.x;
  const int half = (bid & 7) >> 2;          // 0: XCD 0-3, 1: XCD 4-7 (heuristic)
  const int oh   = half ^ 1;
  const int smp  = ((bid >> 3) << 2) | (bid & 3);   // sample 0..127, bijective
  const int u    = tid & 127;               // local unit / class col
  const int kq   = tid >> 7;                // k-quarter 0..3 (LSTM split-K)
  const int U    = (half << 7) | u;         // global unit / class
  const int or0  = kq*2;                    // owned beam rows (epilogue)
  const int or1  = or0 + 1;
  const int wv   = tid >> 6, lane = tid & 63;

  float* xbase = xchg + (size_t)smp*8192;
  unsigned* fme = flags + smp*8 + half;     // use fme[p*2]
  unsigned* fpr = flags + smp*8 + oh;

  float creg[3][2];                         // c for owned rows or0/or1, unit u
  const float bpc = bp[U];

  // ---- init: x0 into jnt[2048..2303]; st = x0 broadcast; prefix ----
  if (tid < 64) *(float4*)&jnt[2048 + tid*4] = *(const float4*)&x[(size_t)smp*256 + tid*4];
  if (tid < 8)  pfx[tid] = (tid==0) ? 0.0f : -1e30f;
  __syncthreads();
  *(float4*)&st[tid*4] = *(const float4*)&jnt[2048 + (tid&63)*4];

  // ---- init LSTM from zero state (M=1); per layer: compute own half, exchange
  for (int l=0; l<3; l++){
    if (tid < 128){
      const float* Wg = wihT + (size_t)l*262144;
      float a0=0.f,a1=0.f,a2=0.f,a3=0.f;
      for (int kc=0; kc<256; kc+=4){
        float4 a4 = *(const float4*)&jnt[2048+kc];
        float4 w0 = *(const float4*)&Wg[(size_t)(kc+0)*1024 + U*4];
        float4 w1 = *(const float4*)&Wg[(size_t)(kc+1)*1024 + U*4];
        float4 w2 = *(const float4*)&Wg[(size_t)(kc+2)*1024 + U*4];
        float4 w3 = *(const float4*)&Wg[(size_t)(kc+3)*1024 + U*4];
        a0=fmaf(a4.x,w0.x,a0); a0=fmaf(a4.y,w1.x,a0); a0=fmaf(a4.z,w2.x,a0); a0=fmaf(a4.w,w3.x,a0);
        a1=fmaf(a4.x,w0.y,a1); a1=fmaf(a4.y,w1.y,a1); a1=fmaf(a4.z,w2.y,a1); a1=fmaf(a4.w,w3.y,a1);
        a2=fmaf(a4.x,w0.z,a2); a2=fmaf(a4.y,w1.z,a2); a2=fmaf(a4.z,w2.z,a2); a2=fmaf(a4.w,w3.z,a2);
        a3=fmaf(a4.x,w0.w,a3); a3=fmaf(a4.y,w1.w,a3); a3=fmaf(a4.z,w2.w,a3); a3=fmaf(a4.w,w3.w,a3);
      }
      float4 bs = *(const float4*)&biasC[(l*256+U)*4];
      float gi=a0+bs.x, gg=a2+bs.z, go=a3+bs.w;  // c_old=0
      float cn = sigf(gi)*tanhf(gg);
      float hn = sigf(go)*tanhf(cn);
      jnt[tid] = hn; jnt[128+tid] = cn;
    }
    __syncthreads();
    {
      float* xm = xbase + (half*4 + (l+1))*1024;
      float hv = jnt[u], cv = jnt[128+u];
      creg[l][0] = cv; creg[l][1] = cv;
      hS[l*2048 + or0*256 + U] = hv;
      hS[l*2048 + or1*256 + U] = hv;
      astoref(&xm[or0*128 + u], hv);
      astoref(&xm[or1*128 + u], hv);
    }
    __syncthreads();   // drains vmcnt: exchange data at MALL
    if (tid==0){
      __hip_atomic_store(&fme[(l+1)*2], 1u, __ATOMIC_RELAXED, __HIP_MEMORY_SCOPE_AGENT);
      while (__hip_atomic_load(&fpr[(l+1)*2], __ATOMIC_RELAXED, __HIP_MEMORY_SCOPE_AGENT) < 1u)
        __builtin_amdgcn_s_sleep(2);
    }
    __syncthreads();
    {
      const float* xr = xbase + (oh*4 + (l+1))*1024;
      int r = tid>>6, u2 = (tid&63)*2;
      float v0 = aloadf(&xr[r*128+u2]);
      float v1 = aloadf(&xr[r*128+u2+1]);
      hS[l*2048 + r*256 + (oh<<7)+u2]   = v0;
      hS[l*2048 + r*256 + (oh<<7)+u2+1] = v1;
      if (l<2 && r==0){ jnt[2048+(oh<<7)+u2] = v0; jnt[2048+(oh<<7)+u2+1] = v1; }
    }
    if (l<2 && tid<128) jnt[2048 + U] = jnt[tid];   // own half of next input row
    __syncthreads();
  }

  // split-K GEMM: ALL 8 rows x 4 gate-cols of unit U over this thread's 64 k's.
  // 2-stage rolling W prefetch (32 VGPR). acc2: row i -> acc2[i*2]={g_i,g_f},
  // acc2[i*2+1]={g_g,g_o}. Every W byte read ONCE per block.
  auto gemm8 = [&](const float* hbaseK, const int* ro, const float* WgK, f2* acc2){
    const float* Wr = WgK + (U<<2);
    float4 wst[2][4];
    #pragma unroll
    for (int s=0; s<2; s++){
      const float* Wn = Wr + (size_t)(s*4)*1024;
      wst[s][0]=*(const float4*)&Wn[0];    wst[s][1]=*(const float4*)&Wn[1024];
      wst[s][2]=*(const float4*)&Wn[2048]; wst[s][3]=*(const float4*)&Wn[3072];
    }
    auto macblk = [&](const float4 wk[4], const float4 a[8]){
      #pragma unroll
      for (int kk=0;kk<4;kk++){
        f2 wlo = {wk[kk].x, wk[kk].y};
        f2 whi = {wk[kk].z, wk[kk].w};
        const float av4[8] = {
          kk==0?a[0].x:(kk==1?a[0].y:(kk==2?a[0].z:a[0].w)),
          kk==0?a[1].x:(kk==1?a[1].y:(kk==2?a[1].z:a[1].w)),
          kk==0?a[2].x:(kk==1?a[2].y:(kk==2?a[2].z:a[2].w)),
          kk==0?a[3].x:(kk==1?a[3].y:(kk==2?a[3].z:a[3].w)),
          kk==0?a[4].x:(kk==1?a[4].y:(kk==2?a[4].z:a[4].w)),
          kk==0?a[5].x:(kk==1?a[5].y:(kk==2?a[5].z:a[5].w)),
          kk==0?a[6].x:(kk==1?a[6].y:(kk==2?a[6].z:a[6].w)),
          kk==0?a[7].x:(kk==1?a[7].y:(kk==2?a[7].z:a[7].w))};
        #pragma unroll
        for (int i=0;i<8;i++){
          f2 av = {av4[i], av4[i]};
          acc2[i*2+0] = fma2(av, wlo, acc2[i*2+0]);
          acc2[i*2+1] = fma2(av, whi, acc2[i*2+1]);
        }
      }
    };
    #pragma unroll 1
    for (int kc=0; kc<56; kc+=8){             // consume k 0..55, refill to 63
      #pragma unroll
      for (int s=0; s<2; s++){
        const int kcur = kc + s*4;
        const float4 wk[4] = {wst[s][0], wst[s][1], wst[s][2], wst[s][3]};
        const float* Wn = Wr + (size_t)(kcur+8)*1024;
        wst[s][0]=*(const float4*)&Wn[0];    wst[s][1]=*(const float4*)&Wn[1024];
        wst[s][2]=*(const float4*)&Wn[2048]; wst[s][3]=*(const float4*)&Wn[3072];
        float4 a[8];
        #pragma unroll
        for (int i=0;i<8;i++) a[i] = *(const float4*)&hbaseK[ro[i] + kcur];
        macblk(wk, a);
      }
    }
    #pragma unroll
    for (int s=0; s<2; s++){                  // tail: k=56..63, no refill
      const int kcur = 56 + s*4;
      const float4 wk[4] = {wst[s][0], wst[s][1], wst[s][2], wst[s][3]};
      float4 a[8];
      #pragma unroll
      for (int i=0;i<8;i++) a[i] = *(const float4*)&hbaseK[ro[i] + kcur];
      macblk(wk, a);
    }
  };

  const int kqb = kq << 6;                  // this thread's 64-k base

  // ---------------- 64 decode steps ----------------
  for (int t=0; t<64; t++){
    // ---- phase3 poll: partner h[2] (+ partner half of st for t>0) ----
    // WpT L2-prefetch in the dead wait (waves 1-7; 4 lines/thread, asm sink)
    if (wv){
      float sum = 0.f;
      const float* pp = WpT + (half<<7);
      #pragma unroll
      for (int j=0;j<4;j++){
        int n = tid + (j<<9);
        sum += pp[((size_t)(n>>3)<<8) + ((n&7)<<4)];
      }
      asm volatile("" :: "v"(sum));
    }
    if (tid==0){
      unsigned want = (unsigned)(t+1);
      while (__hip_atomic_load(&fpr[3*2], __ATOMIC_RELAXED, __HIP_MEMORY_SCOPE_AGENT) < want)
        __builtin_amdgcn_s_sleep(2);
    }
    __syncthreads();
    {
      const float* xr = xbase + (oh*4 + 3)*1024;
      int r = tid>>6, u2 = (tid&63)*2;
      float v0 = aloadf(&xr[r*128+u2]);
      float v1 = aloadf(&xr[r*128+u2+1]);
      hS[2*2048 + r*256 + (oh<<7)+u2]   = v0;
      hS[2*2048 + r*256 + (oh<<7)+u2+1] = v1;
      if (t > 0){
        f2 xv = *(const f2*)&x[(size_t)t*32768 + smp*256 + (oh<<7)+u2];
        st[r*256 + (oh<<7)+u2]   = v0 + xv.x;
        st[r*256 + (oh<<7)+u2+1] = v1 + xv.y;
      }
    }
    __syncthreads();   // st/hS[2] complete

    // ---- proj (R1 verbatim): rows rq*2, rq*2+1, own class col U;
    // full 256-k per thread, 4-stage scalar W prefetch. ----
    {
      const int rq = tid >> 7;                 // 0..3
      const float* A0 = st + (rq*2)*256;
      const float* A1 = st + (rq*2+1)*256;
      const float* Wc = WpT + U;
      f2 q01 = {0.f,0.f};
      float wstp[4][4];
      #pragma unroll
      for (int s=0;s<4;s++){
        #pragma unroll
        for (int q=0;q<4;q++) wstp[s][q] = Wc[(s*4+q)*256];
      }
      #pragma unroll 1
      for (int kc=0; kc<240; kc+=16){
        #pragma unroll
        for (int s=0;s<4;s++){
          const int kcur = kc + s*4;
          float w0=wstp[s][0], w1=wstp[s][1], w2=wstp[s][2], w3=wstp[s][3];
          #pragma unroll
          for (int q=0;q<4;q++) wstp[s][q] = Wc[(kcur+16+q)*256];
          float4 a0 = *(const float4*)&A0[kcur];
          float4 a1 = *(const float4*)&A1[kcur];
          q01 = fma2((f2){a0.x,a1.x}, (f2){w0,w0}, q01);
          q01 = fma2((f2){a0.y,a1.y}, (f2){w1,w1}, q01);
          q01 = fma2((f2){a0.z,a1.z}, (f2){w2,w2}, q01);
          q01 = fma2((f2){a0.w,a1.w}, (f2){w3,w3}, q01);
        }
      }
      #pragma unroll
      for (int s=0;s<4;s++){
        const int kcur = 240 + s*4;
        float w0=wstp[s][0], w1=wstp[s][1], w2=wstp[s][2], w3=wstp[s][3];
        float4 a0 = *(const float4*)&A0[kcur];
        float4 a1 = *(const float4*)&A1[kcur];
        q01 = fma2((f2){a0.x,a1.x}, (f2){w0,w0}, q01);
        q01 = fma2((f2){a0.y,a1.y}, (f2){w1,w1}, q01);
        q01 = fma2((f2){a0.z,a1.z}, (f2){w2,w2}, q01);
        q01 = fma2((f2){a0.w,a1.w}, (f2){w3,w3}, q01);
      }
      float v0 = q01.x + bpc, v1 = q01.y + bpc;
      float* xm = xbase + (half*4 + 0)*1024;
      jnt[(rq*2)*256 + U]   = v0;
      jnt[(rq*2+1)*256 + U] = v1;
      astoref(&xm[(rq*2)*128 + u],   v0);
      astoref(&xm[(rq*2+1)*128 + u], v1);
    }
    __syncthreads();   // jnt own half visible; exchange data at MALL
    if (tid==0)
      __hip_atomic_store(&fme[0], (unsigned)(t+1), __ATOMIC_RELAXED, __HIP_MEMORY_SCOPE_AGENT);
    // LSTM-W L2-prefetch in the dead wait (waves 1-7): whh l0/l1/l2 + wih
    // l1/l2, 16 lines x 5 regions per thread; sum + asm sink (rule #17).
    if (wv){
      float sum = 0.f;
      const float* pw = whhT + ((size_t)half<<9);
      const float* pi = wihT + ((size_t)half<<9);
      #pragma unroll 4
      for (int j=0;j<16;j++){
        int n = tid + (j<<9);
        size_t off = ((size_t)(n>>5)<<10) + ((n&31)<<4);
        sum += pw[off] + pw[262144+off] + pw[524288+off]
             + pi[262144+off] + pi[524288+off];
      }
      asm volatile("" :: "v"(sum));
    }
    if (tid==0){
      while (__hip_atomic_load(&fpr[0], __ATOMIC_RELAXED, __HIP_MEMORY_SCOPE_AGENT) < (unsigned)(t+1))
        __builtin_amdgcn_s_sleep(2);
    }
    __syncthreads();
    {
      const float* xr = xbase + (oh*4 + 0)*1024;
      int r = tid>>6, c2 = (tid&63)*2;
      jnt[r*256 + (oh<<7) + c2]   = aloadf(&xr[r*128+c2]);
      jnt[r*256 + (oh<<7) + c2+1] = aloadf(&xr[r*128+c2+1]);
    }
    __syncthreads();

    // ---- log-softmax + prefix: wave wv handles beam-row wv (redundant x2) ----
    {
      const int kb = wv;
      float4 v = *(const float4*)&jnt[kb*256 + lane*4];
      float m = fmaxf(fmaxf(v.x,v.y),fmaxf(v.z,v.w));
      for (int off=32;off;off>>=1) m = fmaxf(m, __shfl_down(m,off));
      m = __shfl(m, 0);
      double s = exp((double)v.x-(double)m)+exp((double)v.y-(double)m)
               + exp((double)v.z-(double)m)+exp((double)v.w-(double)m);
      for (int off=32;off;off>>=1) s += __shfl_down(s,off);
      s = __shfl(s, 0);
      double lse = log(s);
      float pf = pfx[kb];
      float4 o;
      o.x = (float)((double)v.x - (double)m - lse) + pf;
      o.y = (float)((double)v.y - (double)m - lse) + pf;
      o.z = (float)((double)v.z - (double)m - lse) + pf;
      o.w = (float)((double)v.w - (double)m - lse) + pf;
      *(float4*)&jnt[kb*256+lane*4] = o;
    }
    __syncthreads();

    // ---- top-8: per-wave (= per-row) in-wave top-8, then wave-0 merge ----
    {
      float4 v4 = *(const float4*)&jnt[wv*256 + lane*4];
      float e0=v4.x, e1=v4.y, e2=v4.z, e3=v4.w;
      const int ib = wv*256 + lane*4;
      #pragma unroll 1
      for (int r=0;r<8;r++){
        float bv = e0; int bi = ib;
        if (e1>bv){bv=e1;bi=ib+1;}
        if (e2>bv){bv=e2;bi=ib+2;}
        if (e3>bv){bv=e3;bi=ib+3;}
        #pragma unroll
        for (int off=32;off;off>>=1){
          float ov=__shfl_down(bv,off); int oi=__shfl_down(bi,off);
          if (ov>bv||(ov==bv&&oi<bi)){bv=ov;bi=oi;}
        }
        bi=__shfl(bi,0);
        if (lane==0){ cvS[wv*8+r]=bv; ciS[wv*8+r]=bi; }
        if (bi==ib)        e0=-INFINITY;
        else if (bi==ib+1) e1=-INFINITY;
        else if (bi==ib+2) e2=-INFINITY;
        else if (bi==ib+3) e3=-INFINITY;
      }
    }
    __syncthreads();
    if (wv==0){
      float mv = cvS[lane]; int mi = ciS[lane];
      #pragma unroll 1
      for (int r=0;r<8;r++){
        float bv=mv; int bi=mi;
        #pragma unroll
        for (int off=32;off;off>>=1){
          float ov=__shfl_down(bv,off); int oi=__shfl_down(bi,off);
          if (ov>bv||(ov==bv&&oi<bi)){bv=ov;bi=oi;}
        }
        bv=__shfl(bv,0); bi=__shfl(bi,0);
        if (lane==0){ sVal[r]=bv; sPrev[r]=bi>>8; sCls[r]=bi&255; }
        if (mi==bi) mv=-INFINITY;
      }
    }
    __syncthreads();
    if (tid<8){
      pfx[tid] = sVal[tid];
      prevH[t*8+tid] = (short)sPrev[tid];
      clsH[t*8+tid]  = (short)sCls[tid];
    }
    __syncthreads();

    int rog8[8], rod8[8];
    #pragma unroll
    for (int r=0;r<8;r++){ rog8[r] = sPrev[r]*256; rod8[r] = r*256; }
    const int clr0 = sCls[or0], clr1 = sCls[or1];
    const int pv0  = sPrev[or0], pv1 = sPrev[or1];

    // ---- 3 LSTM layers (unit-split across pair, 4-way split-K in block) ----
    #pragma unroll 1
    for (int l=0; l<3; l++){
      cS[or0*128 + u] = creg[l][0];
      cS[or1*128 + u] = creg[l][1];
      __syncthreads();   // cS visible; hS stable; jnt free

      f2 acc2[16];
      #pragma unroll
      for (int i=0;i<16;i++) acc2[i] = (f2){0.f,0.f};
      // recurrent first (operands resident) -> hides the h[l-1] exchange poll
      gemm8(hS + l*2048 + kqb, rog8,
            whhT + (size_t)l*262144 + (size_t)kqb*1024, acc2);
      if (l > 0){
        if (tid==0){
          unsigned want = (unsigned)(t+2);
          while (__hip_atomic_load(&fpr[l*2], __ATOMIC_RELAXED, __HIP_MEMORY_SCOPE_AGENT) < want)
            __builtin_amdgcn_s_sleep(2);
        }
        __syncthreads();
        {
          const float* xr = xbase + (oh*4 + l)*1024;
          int r = tid>>6, u2 = (tid&63)*2;
          hS[(l-1)*2048 + r*256 + (oh<<7)+u2]   = aloadf(&xr[r*128+u2]);
          hS[(l-1)*2048 + r*256 + (oh<<7)+u2+1] = aloadf(&xr[r*128+u2+1]);
        }
        __syncthreads();
        gemm8(hS + (l-1)*2048 + kqb, rod8,
              wihT + (size_t)l*262144 + (size_t)kqb*1024, acc2);
      }

      // ---- 3-round static XOR-tree reduction (slots: jnt[tid*12], 8 floats) --
      // A1/A2: partner tid^256 (kq^2). kq<2 keeps rows 0-3, kq>=2 keeps 4-7.
      // B: partner tid^128 (kq^1). Final: rows or0=2kq, or1 in G0..G3.
      f2 G0, G1, G2, G3;
      {
        const int dA = (tid ^ 256) * 12;
        const int dB = (tid ^ 128) * 12;
        float4 p0, p1, r0, r1;
        // A1: ship rows {4,5} (kq<2) / {0,1} (kq>=2)
        if (kq < 2){
          p0 = make_float4(acc2[8].x, acc2[8].y, acc2[9].x, acc2[9].y);
          p1 = make_float4(acc2[10].x,acc2[10].y,acc2[11].x,acc2[11].y);
        } else {
          p0 = make_float4(acc2[0].x, acc2[0].y, acc2[1].x, acc2[1].y);
          p1 = make_float4(acc2[2].x, acc2[2].y, acc2[3].x, acc2[3].y);
        }
        *(float4*)&jnt[dA] = p0; *(float4*)&jnt[dA+4] = p1;
        __syncthreads();
        r0 = *(const float4*)&jnt[tid*12];
        r1 = *(const float4*)&jnt[tid*12+4];
        if (kq < 2){
          acc2[0] += (f2){r0.x,r0.y}; acc2[1] += (f2){r0.z,r0.w};
          acc2[2] += (f2){r1.x,r1.y}; acc2[3] += (f2){r1.z,r1.w};
        } else {
          acc2[0] = acc2[8]  + (f2){r0.x,r0.y}; acc2[1] = acc2[9]  + (f2){r0.z,r0.w};
          acc2[2] = acc2[10] + (f2){r1.x,r1.y}; acc2[3] = acc2[11] + (f2){r1.z,r1.w};
        }
        __syncthreads();   // slot reuse
        // A2: ship rows {6,7} (kq<2) / {2,3} (kq>=2)
        if (kq < 2){
          p0 = make_float4(acc2[12].x,acc2[12].y,acc2[13].x,acc2[13].y);
          p1 = make_float4(acc2[14].x,acc2[14].y,acc2[15].x,acc2[15].y);
        } else {
          p0 = make_float4(acc2[4].x, acc2[4].y, acc2[5].x, acc2[5].y);
          p1 = make_float4(acc2[6].x, acc2[6].y, acc2[7].x, acc2[7].y);
        }
        *(float4*)&jnt[dA] = p0; *(float4*)&jnt[dA+4] = p1;
        __syncthreads();
        r0 = *(const float4*)&jnt[tid*12];
        r1 = *(const float4*)&jnt[tid*12+4];
        if (kq < 2){
          acc2[4] += (f2){r0.x,r0.y}; acc2[5] += (f2){r0.z,r0.w};
          acc2[6] += (f2){r1.x,r1.y}; acc2[7] += (f2){r1.z,r1.w};
        } else {
          acc2[4] = acc2[12] + (f2){r0.x,r0.y}; acc2[5] = acc2[13] + (f2){r0.z,r0.w};
          acc2[6] = acc2[14] + (f2){r1.x,r1.y}; acc2[7] = acc2[15] + (f2){r1.z,r1.w};
        }
        __syncthreads();   // slot reuse
        // B: ship the non-owned row pair; keep the owned pair.
        if (kq & 1){
          p0 = make_float4(acc2[0].x, acc2[0].y, acc2[1].x, acc2[1].y);
          p1 = make_float4(acc2[2].x, acc2[2].y, acc2[3].x, acc2[3].y);
        } else {
          p0 = make_float4(acc2[4].x, acc2[4].y, acc2[5].x, acc2[5].y);
          p1 = make_float4(acc2[6].x, acc2[6].y, acc2[7].x, acc2[7].y);
        }
        *(float4*)&jnt[dB] = p0; *(float4*)&jnt[dB+4] = p1;
        __syncthreads();
        r0 = *(const float4*)&jnt[tid*12];
        r1 = *(const float4*)&jnt[tid*12+4];
        f2 k0, k1, k2, k3;
        if (kq & 1){ k0=acc2[4]; k1=acc2[5]; k2=acc2[6]; k3=acc2[7]; }
        else       { k0=acc2[0]; k1=acc2[1]; k2=acc2[2]; k3=acc2[3]; }
        G0 = k0 + (f2){r0.x,r0.y};   // row or0 {i,f}
        G1 = k1 + (f2){r0.z,r0.w};   // row or0 {g,o}
        G2 = k2 + (f2){r1.x,r1.y};   // row or1 {i,f}
        G3 = k3 + (f2){r1.z,r1.w};   // row or1 {g,o}
      }

      // ---- cell epilogue: every thread finalizes its rows or0, or1 ----
      {
        const int tn = (t < 63) ? (t+1) : 63;
        float4 b0, b1;
        if (l==0){
          b0 = *(const float4*)&embW[(size_t)clr0*1024 + U*4];
          b1 = *(const float4*)&embW[(size_t)clr1*1024 + U*4];
        } else {
          b0 = *(const float4*)&biasC[(l*256+U)*4];
          b1 = b0;
        }
        float co0 = cS[pv0*128 + u], co1 = cS[pv1*128 + u];
        float gi0 = G0.x + b0.x, gf0 = G0.y + b0.y;
        float gg0 = G1.x + b0.z, go0 = G1.y + b0.w;
        float cn0 = sigf(gf0)*co0 + sigf(gi0)*tanhf(gg0);
        float hn0 = sigf(go0)*tanhf(cn0);
        float gi1 = G2.x + b1.x, gf1 = G2.y + b1.y;
        float gg1 = G3.x + b1.z, go1 = G3.y + b1.w;
        float cn1 = sigf(gf1)*co1 + sigf(gi1)*tanhf(gg1);
        float hn1 = sigf(go1)*tanhf(cn1);
        creg[l][0] = cn0; creg[l][1] = cn1;
        hS[l*2048 + or0*256 + U] = hn0;
        hS[l*2048 + or1*256 + U] = hn1;
        if (l == 2){
          float xv = x[(size_t)tn*32768 + smp*256 + U];
          st[or0*256 + U] = hn0 + xv;
          st[or1*256 + U] = hn1 + xv;
        }
        float* xm = xbase + (half*4 + (l+1))*1024;
        astoref(&xm[or0*128 + u], hn0);
        astoref(&xm[or1*128 + u], hn1);
      }
      __syncthreads();   // drains vmcnt: h exchange data at MALL before flag
      if (tid==0)
        __hip_atomic_store(&fme[(l+1)*2], (unsigned)(t+2), __ATOMIC_RELAXED, __HIP_MEMORY_SCOPE_AGENT);
    }
  }

  // ---- backtrace choices + prefix (half 0 only; both halves identical) ----
  if (half==0 && tid < 8){
    int e = tid;
    for (int tt=63; tt>=0; --tt){
      out[(size_t)(smp*8+tid)*64 + tt] = (float)clsH[tt*8+e];
      e = (int)prevH[tt*8+e];
    }
    out[65536 + smp*8 + tid] = pfx[tid];
  }
}

extern "C" void kernel_launch(void* const* d_in, const int* in_sizes, int n_in,
                              void* d_out, int out_size, void* d_ws, size_t ws_size,
                              hipStream_t stream)
{
  const float* x   = (const float*)d_in[0];
  const float* emb = (const float*)d_in[1];
  const float* Wih = (const float*)d_in[2];
  const float* Whh = (const float*)d_in[3];
  const float* bih = (const float*)d_in[4];
  const float* bhh = (const float*)d_in[5];
  const float* Wp  = (const float*)d_in[6];
  const float* bp  = (const float*)d_in[7];
  float* ws = (float*)d_ws;

  float* embW  = ws + O_EMBW;
  float* WpT   = ws + O_WPT;
  float* wihT  = ws + O_WIHT;
  float* whhT  = ws + O_WHHT;
  float* biasC = ws + O_BIASC;
  float* xchg  = ws + O_XCHG;
  unsigned* flags = (unsigned*)(ws + O_FLAGS);

  k_prep<<<256,256,0,stream>>>(Wih,Whh,Wp,bih,bhh,wihT,whhT,WpT,biasC, ws + O_FLAGS);
  k_embW<<<256,256,0,stream>>>(emb, wihT, bih, bhh, embW);
  k_decode<<<256,512,0,stream>>>(x, WpT, wihT, whhT, biasC, embW, bp, xchg, flags, (float*)d_out);
}

// Round 6
// 4285.153 us; speedup vs baseline: 1.4660x; 1.4660x over previous
//
#include <hip/hip_runtime.h>
#include <math.h>

// T=64, B=128, H=256, C=256, K=8, L=3.
// Structure: 2 blocks per sample (unit-half split), 256 blocks, 512 threads.
// Lineage: R4 (passing, 4277us) = gemm8 (all-8-rows x 64-k split-K, W read
// once per block) + 3-round static XOR-tree reduction + R1 proj (verbatim).
// THIS ROUND: R4 + wave-parallel top-8 ONLY. R5's L2 W-prefetch is REVERTED:
// it added +640MB FETCH/dispatch (1.41->2.05GB) and +1.8ms -- prefetching
// into an at-capacity L2 thrashes the resident weight set and competes with
// the co-resident block's critical-path loads. Do not re-add.
// Wave-parallel top-8 (verified correct in R5): wave wv == beam-row wv does
// an in-wave 8-round top-8 of its 256 logits (no barriers), wave 0 merges
// the 64 candidates in-wave. Replaces 16 block barriers + 8 serial-tid0
// scans with 2 barriers. Tie-break (val, lowest-idx) preserved; both blocks
// compute bit-identical selections from identical jnt contents.
// Pair-sync: relaxed agent-scope atomics + monotonic flags (no acquire/release
// so L2 weight residency survives); writer: data -> __syncthreads (vmcnt
// drain) -> tid0 posts flag; reader: tid0 polls -> barrier -> loads. Flags
// zeroed by k_prep each launch (graph-replay safe).
static constexpr size_t O_EMBW  = 0;         // [256 cls][1024 (u*4+g)]  emb@Wih0^T + b0
static constexpr size_t O_WPT   = 262144;    // [256 k][256 c]
static constexpr size_t O_WIHT  = 327680;    // [3][256 k][1024 (u*4+g)]
static constexpr size_t O_WHHT  = 1114112;   // [3][256 k][1024 (u*4+g)]
static constexpr size_t O_BIASC = 1900544;   // [3][256 u][4 g]  bih+bhh
static constexpr size_t O_XCHG  = 1903616;   // [128 smp][2 half][4 phase][1024] floats
static constexpr size_t O_FLAGS = 2952192;   // 1024 uint32: [smp][4 phase][2 half]
// total 2953216 floats ≈ 11.8 MB

typedef float f2 __attribute__((ext_vector_type(2)));
__device__ __forceinline__ f2 fma2(f2 a, f2 b, f2 c){ return __builtin_elementwise_fma(a,b,c); }
__device__ __forceinline__ float sigf(float x){ return 1.0f/(1.0f + expf(-x)); }

__device__ __forceinline__ void astoref(float* p, float v){
  __hip_atomic_store(p, v, __ATOMIC_RELAXED, __HIP_MEMORY_SCOPE_AGENT);
}
__device__ __forceinline__ float aloadf(const float* p){
  return __hip_atomic_load((float*)p, __ATOMIC_RELAXED, __HIP_MEMORY_SCOPE_AGENT);
}

// ---------------- one-time prep: transposes + combined biases + flag reset ----
__global__ __launch_bounds__(256) void k_prep(
    const float* __restrict__ Wih, const float* __restrict__ Whh,
    const float* __restrict__ Wp,  const float* __restrict__ bih,
    const float* __restrict__ bhh,
    float* __restrict__ wihT, float* __restrict__ whhT,
    float* __restrict__ WpT, float* __restrict__ biasC,
    float* __restrict__ flagsF)
{
  const int NT = 786432;
  const int TOTAL = 2*NT + 65536 + 3072 + 1024;
  int stride = gridDim.x * blockDim.x;
  for (int i = blockIdx.x*blockDim.x + threadIdx.x; i < TOTAL; i += stride){
    if (i < NT){
      int l = i / 262144, r = i % 262144;      // r = row*256 + k
      int row = r >> 8, k = r & 255;
      int g = row >> 8, uu = row & 255;
      wihT[(size_t)l*262144 + (k<<10) + (uu<<2) + g] = Wih[i];
    } else if (i < 2*NT){
      int j = i - NT;
      int l = j / 262144, r = j % 262144;
      int row = r >> 8, k = r & 255;
      int g = row >> 8, uu = row & 255;
      whhT[(size_t)l*262144 + (k<<10) + (uu<<2) + g] = Whh[j];
    } else if (i < 2*NT + 65536){
      int j = i - 2*NT; int c = j >> 8, k = j & 255;
      WpT[(k<<8) + c] = Wp[j];
    } else if (i < 2*NT + 65536 + 3072){
      int j = i - 2*NT - 65536;          // [3][256][4]
      int l = j >> 10; int cg = j & 1023, uu = cg >> 2, g = cg & 3;
      biasC[j] = bih[l*1024 + g*256 + uu] + bhh[l*1024 + g*256 + uu];
    } else {
      flagsF[i - (2*NT + 65536 + 3072)] = 0.0f;   // zero sync flags every launch
    }
  }
}

// ------------- one-time: embW[cls][u*4+g] = emb@Wih0^T + bih0 + bhh0 ---------
__global__ __launch_bounds__(256) void k_embW(
    const float* __restrict__ emb, const float* __restrict__ wih0T,
    const float* __restrict__ bih, const float* __restrict__ bhh,
    float* __restrict__ embW)
{
  const int cls = blockIdx.x, uu = threadIdx.x;
  const float* er = emb + cls*256;
  float a0=0.f,a1=0.f,a2=0.f,a3=0.f;
  for (int k=0;k<256;k++){
    float ev = er[k];
    float4 w = *(const float4*)&wih0T[k*1024 + uu*4];
    a0 = fmaf(ev, w.x, a0); a1 = fmaf(ev, w.y, a1);
    a2 = fmaf(ev, w.z, a2); a3 = fmaf(ev, w.w, a3);
  }
  a0 += bih[uu]       + bhh[uu];
  a1 += bih[256+uu]   + bhh[256+uu];
  a2 += bih[512+uu]   + bhh[512+uu];
  a3 += bih[768+uu]   + bhh[768+uu];
  *(float4*)&embW[cls*1024 + uu*4] = make_float4(a0,a1,a2,a3);
}

// ---------------- decode: 2 blocks = 1 sample, 512 threads each --------------
__global__
__attribute__((amdgpu_flat_work_group_size(512,512)))
void k_decode(
    const float* __restrict__ x,      // [64][128][256]
    const float* __restrict__ WpT,    // [256 k][256 c]
    const float* __restrict__ wihT,   // [3][256 k][1024]
    const float* __restrict__ whhT,   // [3][256 k][1024]
    const float* __restrict__ biasC,  // [3][256 u][4 g]
    const float* __restrict__ embW,   // [256 cls][1024]
    const float* __restrict__ bp,     // [256]
    float* __restrict__ xchg,         // [128][2][4][1024]
    unsigned* __restrict__ flags,     // [128][4][2]
    float* __restrict__ out)
{
  __shared__ float hS[3*2048];   // h[l][row][unit 0..255] FULL width   24 KB
  __shared__ float cS[1024];     // staged c_old[row][own-unit 0..127]   4 KB
  __shared__ float st[2048];     // state[row][unit] FULL width          8 KB
  __shared__ float jnt[6144];    // logits / reduction slots (512x12)   24 KB
  __shared__ float pfx[8];
  __shared__ float cvS[64]; __shared__ int ciS[64];   // top-8 candidates
  __shared__ float sVal[8]; __shared__ int sPrev[8], sCls[8];
  __shared__ short prevH[512], clsH[512];

  const int tid  = threadIdx.x;
  const int bid  = blockIdx.x;
  const int half = (bid & 7) >> 2;          // 0: XCD 0-3, 1: XCD 4-7 (heuristic)
  const int oh   = half ^ 1;
  const int smp  = ((bid >> 3) << 2) | (bid & 3);   // sample 0..127, bijective
  const int u    = tid & 127;               // local unit / class col
  const int kq   = tid >> 7;                // k-quarter 0..3 (LSTM split-K)
  const int U    = (half << 7) | u;         // global unit / class
  const int or0  = kq*2;                    // owned beam rows (epilogue)
  const int or1  = or0 + 1;
  const int wv   = tid >> 6, lane = tid & 63;

  float* xbase = xchg + (size_t)smp*8192;
  unsigned* fme = flags + smp*8 + half;     // use fme[p*2]
  unsigned* fpr = flags + smp*8 + oh;

  float creg[3][2];                         // c for owned rows or0/or1, unit u
  const float bpc = bp[U];

  // ---- init: x0 into jnt[2048..2303]; st = x0 broadcast; prefix ----
  if (tid < 64) *(float4*)&jnt[2048 + tid*4] = *(const float4*)&x[(size_t)smp*256 + tid*4];
  if (tid < 8)  pfx[tid] = (tid==0) ? 0.0f : -1e30f;
  __syncthreads();
  *(float4*)&st[tid*4] = *(const float4*)&jnt[2048 + (tid&63)*4];

  // ---- init LSTM from zero state (M=1); per layer: compute own half, exchange
  for (int l=0; l<3; l++){
    if (tid < 128){
      const float* Wg = wihT + (size_t)l*262144;
      float a0=0.f,a1=0.f,a2=0.f,a3=0.f;
      for (int kc=0; kc<256; kc+=4){
        float4 a4 = *(const float4*)&jnt[2048+kc];
        float4 w0 = *(const float4*)&Wg[(size_t)(kc+0)*1024 + U*4];
        float4 w1 = *(const float4*)&Wg[(size_t)(kc+1)*1024 + U*4];
        float4 w2 = *(const float4*)&Wg[(size_t)(kc+2)*1024 + U*4];
        float4 w3 = *(const float4*)&Wg[(size_t)(kc+3)*1024 + U*4];
        a0=fmaf(a4.x,w0.x,a0); a0=fmaf(a4.y,w1.x,a0); a0=fmaf(a4.z,w2.x,a0); a0=fmaf(a4.w,w3.x,a0);
        a1=fmaf(a4.x,w0.y,a1); a1=fmaf(a4.y,w1.y,a1); a1=fmaf(a4.z,w2.y,a1); a1=fmaf(a4.w,w3.y,a1);
        a2=fmaf(a4.x,w0.z,a2); a2=fmaf(a4.y,w1.z,a2); a2=fmaf(a4.z,w2.z,a2); a2=fmaf(a4.w,w3.z,a2);
        a3=fmaf(a4.x,w0.w,a3); a3=fmaf(a4.y,w1.w,a3); a3=fmaf(a4.z,w2.w,a3); a3=fmaf(a4.w,w3.w,a3);
      }
      float4 bs = *(const float4*)&biasC[(l*256+U)*4];
      float gi=a0+bs.x, gg=a2+bs.z, go=a3+bs.w;  // c_old=0
      float cn = sigf(gi)*tanhf(gg);
      float hn = sigf(go)*tanhf(cn);
      jnt[tid] = hn; jnt[128+tid] = cn;
    }
    __syncthreads();
    {
      float* xm = xbase + (half*4 + (l+1))*1024;
      float hv = jnt[u], cv = jnt[128+u];
      creg[l][0] = cv; creg[l][1] = cv;
      hS[l*2048 + or0*256 + U] = hv;
      hS[l*2048 + or1*256 + U] = hv;
      astoref(&xm[or0*128 + u], hv);
      astoref(&xm[or1*128 + u], hv);
    }
    __syncthreads();   // drains vmcnt: exchange data at MALL
    if (tid==0){
      __hip_atomic_store(&fme[(l+1)*2], 1u, __ATOMIC_RELAXED, __HIP_MEMORY_SCOPE_AGENT);
      while (__hip_atomic_load(&fpr[(l+1)*2], __ATOMIC_RELAXED, __HIP_MEMORY_SCOPE_AGENT) < 1u)
        __builtin_amdgcn_s_sleep(2);
    }
    __syncthreads();
    {
      const float* xr = xbase + (oh*4 + (l+1))*1024;
      int r = tid>>6, u2 = (tid&63)*2;
      float v0 = aloadf(&xr[r*128+u2]);
      float v1 = aloadf(&xr[r*128+u2+1]);
      hS[l*2048 + r*256 + (oh<<7)+u2]   = v0;
      hS[l*2048 + r*256 + (oh<<7)+u2+1] = v1;
      if (l<2 && r==0){ jnt[2048+(oh<<7)+u2] = v0; jnt[2048+(oh<<7)+u2+1] = v1; }
    }
    if (l<2 && tid<128) jnt[2048 + U] = jnt[tid];   // own half of next input row
    __syncthreads();
  }

  // split-K GEMM: ALL 8 rows x 4 gate-cols of unit U over this thread's 64 k's.
  // 2-stage rolling W prefetch (32 VGPR). acc2: row i -> acc2[i*2]={g_i,g_f},
  // acc2[i*2+1]={g_g,g_o}. Every W byte read ONCE per block.
  auto gemm8 = [&](const float* hbaseK, const int* ro, const float* WgK, f2* acc2){
    const float* Wr = WgK + (U<<2);
    float4 wst[2][4];
    #pragma unroll
    for (int s=0; s<2; s++){
      const float* Wn = Wr + (size_t)(s*4)*1024;
      wst[s][0]=*(const float4*)&Wn[0];    wst[s][1]=*(const float4*)&Wn[1024];
      wst[s][2]=*(const float4*)&Wn[2048]; wst[s][3]=*(const float4*)&Wn[3072];
    }
    auto macblk = [&](const float4 wk[4], const float4 a[8]){
      #pragma unroll
      for (int kk=0;kk<4;kk++){
        f2 wlo = {wk[kk].x, wk[kk].y};
        f2 whi = {wk[kk].z, wk[kk].w};
        const float av4[8] = {
          kk==0?a[0].x:(kk==1?a[0].y:(kk==2?a[0].z:a[0].w)),
          kk==0?a[1].x:(kk==1?a[1].y:(kk==2?a[1].z:a[1].w)),
          kk==0?a[2].x:(kk==1?a[2].y:(kk==2?a[2].z:a[2].w)),
          kk==0?a[3].x:(kk==1?a[3].y:(kk==2?a[3].z:a[3].w)),
          kk==0?a[4].x:(kk==1?a[4].y:(kk==2?a[4].z:a[4].w)),
          kk==0?a[5].x:(kk==1?a[5].y:(kk==2?a[5].z:a[5].w)),
          kk==0?a[6].x:(kk==1?a[6].y:(kk==2?a[6].z:a[6].w)),
          kk==0?a[7].x:(kk==1?a[7].y:(kk==2?a[7].z:a[7].w))};
        #pragma unroll
        for (int i=0;i<8;i++){
          f2 av = {av4[i], av4[i]};
          acc2[i*2+0] = fma2(av, wlo, acc2[i*2+0]);
          acc2[i*2+1] = fma2(av, whi, acc2[i*2+1]);
        }
      }
    };
    #pragma unroll 1
    for (int kc=0; kc<56; kc+=8){             // consume k 0..55, refill to 63
      #pragma unroll
      for (int s=0; s<2; s++){
        const int kcur = kc + s*4;
        const float4 wk[4] = {wst[s][0], wst[s][1], wst[s][2], wst[s][3]};
        const float* Wn = Wr + (size_t)(kcur+8)*1024;
        wst[s][0]=*(const float4*)&Wn[0];    wst[s][1]=*(const float4*)&Wn[1024];
        wst[s][2]=*(const float4*)&Wn[2048]; wst[s][3]=*(const float4*)&Wn[3072];
        float4 a[8];
        #pragma unroll
        for (int i=0;i<8;i++) a[i] = *(const float4*)&hbaseK[ro[i] + kcur];
        macblk(wk, a);
      }
    }
    #pragma unroll
    for (int s=0; s<2; s++){                  // tail: k=56..63, no refill
      const int kcur = 56 + s*4;
      const float4 wk[4] = {wst[s][0], wst[s][1], wst[s][2], wst[s][3]};
      float4 a[8];
      #pragma unroll
      for (int i=0;i<8;i++) a[i] = *(const float4*)&hbaseK[ro[i] + kcur];
      macblk(wk, a);
    }
  };

  const int kqb = kq << 6;                  // this thread's 64-k base

  // ---------------- 64 decode steps ----------------
  for (int t=0; t<64; t++){
    // ---- phase3 poll: partner h[2] (+ partner half of st for t>0) ----
    if (tid==0){
      unsigned want = (unsigned)(t+1);
      while (__hip_atomic_load(&fpr[3*2], __ATOMIC_RELAXED, __HIP_MEMORY_SCOPE_AGENT) < want)
        __builtin_amdgcn_s_sleep(2);
    }
    __syncthreads();
    {
      const float* xr = xbase + (oh*4 + 3)*1024;
      int r = tid>>6, u2 = (tid&63)*2;
      float v0 = aloadf(&xr[r*128+u2]);
      float v1 = aloadf(&xr[r*128+u2+1]);
      hS[2*2048 + r*256 + (oh<<7)+u2]   = v0;
      hS[2*2048 + r*256 + (oh<<7)+u2+1] = v1;
      if (t > 0){
        f2 xv = *(const f2*)&x[(size_t)t*32768 + smp*256 + (oh<<7)+u2];
        st[r*256 + (oh<<7)+u2]   = v0 + xv.x;
        st[r*256 + (oh<<7)+u2+1] = v1 + xv.y;
      }
    }
    __syncthreads();   // st/hS[2] complete

    // ---- proj (R1 verbatim): rows rq*2, rq*2+1, own class col U;
    // full 256-k per thread, 4-stage scalar W prefetch. ----
    {
      const int rq = tid >> 7;                 // 0..3
      const float* A0 = st + (rq*2)*256;
      const float* A1 = st + (rq*2+1)*256;
      const float* Wc = WpT + U;
      f2 q01 = {0.f,0.f};
      float wstp[4][4];
      #pragma unroll
      for (int s=0;s<4;s++){
        #pragma unroll
        for (int q=0;q<4;q++) wstp[s][q] = Wc[(s*4+q)*256];
      }
      #pragma unroll 1
      for (int kc=0; kc<240; kc+=16){
        #pragma unroll
        for (int s=0;s<4;s++){
          const int kcur = kc + s*4;
          float w0=wstp[s][0], w1=wstp[s][1], w2=wstp[s][2], w3=wstp[s][3];
          #pragma unroll
          for (int q=0;q<4;q++) wstp[s][q] = Wc[(kcur+16+q)*256];
          float4 a0 = *(const float4*)&A0[kcur];
          float4 a1 = *(const float4*)&A1[kcur];
          q01 = fma2((f2){a0.x,a1.x}, (f2){w0,w0}, q01);
          q01 = fma2((f2){a0.y,a1.y}, (f2){w1,w1}, q01);
          q01 = fma2((f2){a0.z,a1.z}, (f2){w2,w2}, q01);
          q01 = fma2((f2){a0.w,a1.w}, (f2){w3,w3}, q01);
        }
      }
      #pragma unroll
      for (int s=0;s<4;s++){
        const int kcur = 240 + s*4;
        float w0=wstp[s][0], w1=wstp[s][1], w2=wstp[s][2], w3=wstp[s][3];
        float4 a0 = *(const float4*)&A0[kcur];
        float4 a1 = *(const float4*)&A1[kcur];
        q01 = fma2((f2){a0.x,a1.x}, (f2){w0,w0}, q01);
        q01 = fma2((f2){a0.y,a1.y}, (f2){w1,w1}, q01);
        q01 = fma2((f2){a0.z,a1.z}, (f2){w2,w2}, q01);
        q01 = fma2((f2){a0.w,a1.w}, (f2){w3,w3}, q01);
      }
      float v0 = q01.x + bpc, v1 = q01.y + bpc;
      float* xm = xbase + (half*4 + 0)*1024;
      jnt[(rq*2)*256 + U]   = v0;
      jnt[(rq*2+1)*256 + U] = v1;
      astoref(&xm[(rq*2)*128 + u],   v0);
      astoref(&xm[(rq*2+1)*128 + u], v1);
    }
    __syncthreads();   // jnt own half visible; exchange data at MALL
    if (tid==0){
      __hip_atomic_store(&fme[0], (unsigned)(t+1), __ATOMIC_RELAXED, __HIP_MEMORY_SCOPE_AGENT);
      while (__hip_atomic_load(&fpr[0], __ATOMIC_RELAXED, __HIP_MEMORY_SCOPE_AGENT) < (unsigned)(t+1))
        __builtin_amdgcn_s_sleep(2);
    }
    __syncthreads();
    {
      const float* xr = xbase + (oh*4 + 0)*1024;
      int r = tid>>6, c2 = (tid&63)*2;
      jnt[r*256 + (oh<<7) + c2]   = aloadf(&xr[r*128+c2]);
      jnt[r*256 + (oh<<7) + c2+1] = aloadf(&xr[r*128+c2+1]);
    }
    __syncthreads();

    // ---- log-softmax + prefix: wave wv handles beam-row wv (redundant x2) ----
    {
      const int kb = wv;
      float4 v = *(const float4*)&jnt[kb*256 + lane*4];
      float m = fmaxf(fmaxf(v.x,v.y),fmaxf(v.z,v.w));
      for (int off=32;off;off>>=1) m = fmaxf(m, __shfl_down(m,off));
      m = __shfl(m, 0);
      double s = exp((double)v.x-(double)m)+exp((double)v.y-(double)m)
               + exp((double)v.z-(double)m)+exp((double)v.w-(double)m);
      for (int off=32;off;off>>=1) s += __shfl_down(s,off);
      s = __shfl(s, 0);
      double lse = log(s);
      float pf = pfx[kb];
      float4 o;
      o.x = (float)((double)v.x - (double)m - lse) + pf;
      o.y = (float)((double)v.y - (double)m - lse) + pf;
      o.z = (float)((double)v.z - (double)m - lse) + pf;
      o.w = (float)((double)v.w - (double)m - lse) + pf;
      *(float4*)&jnt[kb*256+lane*4] = o;
    }
    __syncthreads();

    // ---- top-8: per-wave (= per-row) in-wave top-8, then wave-0 merge ----
    {
      float4 v4 = *(const float4*)&jnt[wv*256 + lane*4];
      float e0=v4.x, e1=v4.y, e2=v4.z, e3=v4.w;
      const int ib = wv*256 + lane*4;
      #pragma unroll 1
      for (int r=0;r<8;r++){
        float bv = e0; int bi = ib;
        if (e1>bv){bv=e1;bi=ib+1;}
        if (e2>bv){bv=e2;bi=ib+2;}
        if (e3>bv){bv=e3;bi=ib+3;}
        #pragma unroll
        for (int off=32;off;off>>=1){
          float ov=__shfl_down(bv,off); int oi=__shfl_down(bi,off);
          if (ov>bv||(ov==bv&&oi<bi)){bv=ov;bi=oi;}
        }
        bi=__shfl(bi,0);
        if (lane==0){ cvS[wv*8+r]=bv; ciS[wv*8+r]=bi; }
        if (bi==ib)        e0=-INFINITY;
        else if (bi==ib+1) e1=-INFINITY;
        else if (bi==ib+2) e2=-INFINITY;
        else if (bi==ib+3) e3=-INFINITY;
      }
    }
    __syncthreads();
    if (wv==0){
      float mv = cvS[lane]; int mi = ciS[lane];
      #pragma unroll 1
      for (int r=0;r<8;r++){
        float bv=mv; int bi=mi;
        #pragma unroll
        for (int off=32;off;off>>=1){
          float ov=__shfl_down(bv,off); int oi=__shfl_down(bi,off);
          if (ov>bv||(ov==bv&&oi<bi)){bv=ov;bi=oi;}
        }
        bv=__shfl(bv,0); bi=__shfl(bi,0);
        if (lane==0){ sVal[r]=bv; sPrev[r]=bi>>8; sCls[r]=bi&255; }
        if (mi==bi) mv=-INFINITY;
      }
    }
    __syncthreads();
    if (tid<8){
      pfx[tid] = sVal[tid];
      prevH[t*8+tid] = (short)sPrev[tid];
      clsH[t*8+tid]  = (short)sCls[tid];
    }
    __syncthreads();

    int rog8[8], rod8[8];
    #pragma unroll
    for (int r=0;r<8;r++){ rog8[r] = sPrev[r]*256; rod8[r] = r*256; }
    const int clr0 = sCls[or0], clr1 = sCls[or1];
    const int pv0  = sPrev[or0], pv1 = sPrev[or1];

    // ---- 3 LSTM layers (unit-split across pair, 4-way split-K in block) ----
    #pragma unroll 1
    for (int l=0; l<3; l++){
      cS[or0*128 + u] = creg[l][0];
      cS[or1*128 + u] = creg[l][1];
      __syncthreads();   // cS visible; hS stable; jnt free

      f2 acc2[16];
      #pragma unroll
      for (int i=0;i<16;i++) acc2[i] = (f2){0.f,0.f};
      // recurrent first (operands resident) -> hides the h[l-1] exchange poll
      gemm8(hS + l*2048 + kqb, rog8,
            whhT + (size_t)l*262144 + (size_t)kqb*1024, acc2);
      if (l > 0){
        if (tid==0){
          unsigned want = (unsigned)(t+2);
          while (__hip_atomic_load(&fpr[l*2], __ATOMIC_RELAXED, __HIP_MEMORY_SCOPE_AGENT) < want)
            __builtin_amdgcn_s_sleep(2);
        }
        __syncthreads();
        {
          const float* xr = xbase + (oh*4 + l)*1024;
          int r = tid>>6, u2 = (tid&63)*2;
          hS[(l-1)*2048 + r*256 + (oh<<7)+u2]   = aloadf(&xr[r*128+u2]);
          hS[(l-1)*2048 + r*256 + (oh<<7)+u2+1] = aloadf(&xr[r*128+u2+1]);
        }
        __syncthreads();
        gemm8(hS + (l-1)*2048 + kqb, rod8,
              wihT + (size_t)l*262144 + (size_t)kqb*1024, acc2);
      }

      // ---- 3-round static XOR-tree reduction (slots: jnt[tid*12], 8 floats) --
      // A1/A2: partner tid^256 (kq^2). kq<2 keeps rows 0-3, kq>=2 keeps 4-7.
      // B: partner tid^128 (kq^1). Final: rows or0=2kq, or1 in G0..G3.
      f2 G0, G1, G2, G3;
      {
        const int dA = (tid ^ 256) * 12;
        const int dB = (tid ^ 128) * 12;
        float4 p0, p1, r0, r1;
        // A1: ship rows {4,5} (kq<2) / {0,1} (kq>=2)
        if (kq < 2){
          p0 = make_float4(acc2[8].x, acc2[8].y, acc2[9].x, acc2[9].y);
          p1 = make_float4(acc2[10].x,acc2[10].y,acc2[11].x,acc2[11].y);
        } else {
          p0 = make_float4(acc2[0].x, acc2[0].y, acc2[1].x, acc2[1].y);
          p1 = make_float4(acc2[2].x, acc2[2].y, acc2[3].x, acc2[3].y);
        }
        *(float4*)&jnt[dA] = p0; *(float4*)&jnt[dA+4] = p1;
        __syncthreads();
        r0 = *(const float4*)&jnt[tid*12];
        r1 = *(const float4*)&jnt[tid*12+4];
        if (kq < 2){
          acc2[0] += (f2){r0.x,r0.y}; acc2[1] += (f2){r0.z,r0.w};
          acc2[2] += (f2){r1.x,r1.y}; acc2[3] += (f2){r1.z,r1.w};
        } else {
          acc2[0] = acc2[8]  + (f2){r0.x,r0.y}; acc2[1] = acc2[9]  + (f2){r0.z,r0.w};
          acc2[2] = acc2[10] + (f2){r1.x,r1.y}; acc2[3] = acc2[11] + (f2){r1.z,r1.w};
        }
        __syncthreads();   // slot reuse
        // A2: ship rows {6,7} (kq<2) / {2,3} (kq>=2)
        if (kq < 2){
          p0 = make_float4(acc2[12].x,acc2[12].y,acc2[13].x,acc2[13].y);
          p1 = make_float4(acc2[14].x,acc2[14].y,acc2[15].x,acc2[15].y);
        } else {
          p0 = make_float4(acc2[4].x, acc2[4].y, acc2[5].x, acc2[5].y);
          p1 = make_float4(acc2[6].x, acc2[6].y, acc2[7].x, acc2[7].y);
        }
        *(float4*)&jnt[dA] = p0; *(float4*)&jnt[dA+4] = p1;
        __syncthreads();
        r0 = *(const float4*)&jnt[tid*12];
        r1 = *(const float4*)&jnt[tid*12+4];
        if (kq < 2){
          acc2[4] += (f2){r0.x,r0.y}; acc2[5] += (f2){r0.z,r0.w};
          acc2[6] += (f2){r1.x,r1.y}; acc2[7] += (f2){r1.z,r1.w};
        } else {
          acc2[4] = acc2[12] + (f2){r0.x,r0.y}; acc2[5] = acc2[13] + (f2){r0.z,r0.w};
          acc2[6] = acc2[14] + (f2){r1.x,r1.y}; acc2[7] = acc2[15] + (f2){r1.z,r1.w};
        }
        __syncthreads();   // slot reuse
        // B: ship the non-owned row pair; keep the owned pair.
        if (kq & 1){
          p0 = make_float4(acc2[0].x, acc2[0].y, acc2[1].x, acc2[1].y);
          p1 = make_float4(acc2[2].x, acc2[2].y, acc2[3].x, acc2[3].y);
        } else {
          p0 = make_float4(acc2[4].x, acc2[4].y, acc2[5].x, acc2[5].y);
          p1 = make_float4(acc2[6].x, acc2[6].y, acc2[7].x, acc2[7].y);
        }
        *(float4*)&jnt[dB] = p0; *(float4*)&jnt[dB+4] = p1;
        __syncthreads();
        r0 = *(const float4*)&jnt[tid*12];
        r1 = *(const float4*)&jnt[tid*12+4];
        f2 k0, k1, k2, k3;
        if (kq & 1){ k0=acc2[4]; k1=acc2[5]; k2=acc2[6]; k3=acc2[7]; }
        else       { k0=acc2[0]; k1=acc2[1]; k2=acc2[2]; k3=acc2[3]; }
        G0 = k0 + (f2){r0.x,r0.y};   // row or0 {i,f}
        G1 = k1 + (f2){r0.z,r0.w};   // row or0 {g,o}
        G2 = k2 + (f2){r1.x,r1.y};   // row or1 {i,f}
        G3 = k3 + (f2){r1.z,r1.w};   // row or1 {g,o}
      }

      // ---- cell epilogue: every thread finalizes its rows or0, or1 ----
      {
        const int tn = (t < 63) ? (t+1) : 63;
        float4 b0, b1;
        if (l==0){
          b0 = *(const float4*)&embW[(size_t)clr0*1024 + U*4];
          b1 = *(const float4*)&embW[(size_t)clr1*1024 + U*4];
        } else {
          b0 = *(const float4*)&biasC[(l*256+U)*4];
          b1 = b0;
        }
        float co0 = cS[pv0*128 + u], co1 = cS[pv1*128 + u];
        float gi0 = G0.x + b0.x, gf0 = G0.y + b0.y;
        float gg0 = G1.x + b0.z, go0 = G1.y + b0.w;
        float cn0 = sigf(gf0)*co0 + sigf(gi0)*tanhf(gg0);
        float hn0 = sigf(go0)*tanhf(cn0);
        float gi1 = G2.x + b1.x, gf1 = G2.y + b1.y;
        float gg1 = G3.x + b1.z, go1 = G3.y + b1.w;
        float cn1 = sigf(gf1)*co1 + sigf(gi1)*tanhf(gg1);
        float hn1 = sigf(go1)*tanhf(cn1);
        creg[l][0] = cn0; creg[l][1] = cn1;
        hS[l*2048 + or0*256 + U] = hn0;
        hS[l*2048 + or1*256 + U] = hn1;
        if (l == 2){
          float xv = x[(size_t)tn*32768 + smp*256 + U];
          st[or0*256 + U] = hn0 + xv;
          st[or1*256 + U] = hn1 + xv;
        }
        float* xm = xbase + (half*4 + (l+1))*1024;
        astoref(&xm[or0*128 + u], hn0);
        astoref(&xm[or1*128 + u], hn1);
      }
      __syncthreads();   // drains vmcnt: h exchange data at MALL before flag
      if (tid==0)
        __hip_atomic_store(&fme[(l+1)*2], (unsigned)(t+2), __ATOMIC_RELAXED, __HIP_MEMORY_SCOPE_AGENT);
    }
  }

  // ---- backtrace choices + prefix (half 0 only; both halves identical) ----
  if (half==0 && tid < 8){
    int e = tid;
    for (int tt=63; tt>=0; --tt){
      out[(size_t)(smp*8+tid)*64 + tt] = (float)clsH[tt*8+e];
      e = (int)prevH[tt*8+e];
    }
    out[65536 + smp*8 + tid] = pfx[tid];
  }
}

extern "C" void kernel_launch(void* const* d_in, const int* in_sizes, int n_in,
                              void* d_out, int out_size, void* d_ws, size_t ws_size,
                              hipStream_t stream)
{
  const float* x   = (const float*)d_in[0];
  const float* emb = (const float*)d_in[1];
  const float* Wih = (const float*)d_in[2];
  const float* Whh = (const float*)d_in[3];
  const float* bih = (const float*)d_in[4];
  const float* bhh = (const float*)d_in[5];
  const float* Wp  = (const float*)d_in[6];
  const float* bp  = (const float*)d_in[7];
  float* ws = (float*)d_ws;

  float* embW  = ws + O_EMBW;
  float* WpT   = ws + O_WPT;
  float* wihT  = ws + O_WIHT;
  float* whhT  = ws + O_WHHT;
  float* biasC = ws + O_BIASC;
  float* xchg  = ws + O_XCHG;
  unsigned* flags = (unsigned*)(ws + O_FLAGS);

  k_prep<<<256,256,0,stream>>>(Wih,Whh,Wp,bih,bhh,wihT,whhT,WpT,biasC, ws + O_FLAGS);
  k_embW<<<256,256,0,stream>>>(emb, wihT, bih, bhh, embW);
  k_decode<<<256,512,0,stream>>>(x, WpT, wihT, whhT, biasC, embW, bp, xchg, flags, (float*)d_out);
}

// Round 8
// 4157.437 us; speedup vs baseline: 1.5110x; 1.0307x over previous
//
#include <hip/hip_runtime.h>
#include <math.h>

// T=64, B=128, H=256, C=256, K=8, L=3.
// Structure: 2 blocks per sample (unit-half split), 256 blocks, 512 threads.
// Lineage: R6 (passing, 4285us) = gemm8 + XOR-tree + R1 proj + wave top-8.
// THIS ROUND (resubmit of R7 after infra failure; pure LAYOUT change, no
// sync/reduction changes): contiguous per-half weight copies. R6's
// FETCH=1.38GB/dispatch minus ~260MB xchg reads = ~1.1GB/step-aggregate of W
// refetch from HBM (~70% of the 3.1MB/XCD set per step): the strided
// half-slice layouts (2KB of every 4KB row) alias L2 sets (stride-4KB ->
// half the sets used -> ~2MB effective < 3.1MB set) and thrash. New layouts
// stream DENSE contiguous per-half regions:
//   wihTc/whhTc[half][l][256 k][512 (u_local*4+g)]
//   WpTc[half][256 k][128 c_local]   embWc[half][256 cls][512]
// Same total bytes; same workspace offsets; k_prep/k_embW indexing and
// k_decode W base/strides updated; everything else R6-verbatim.
// DO NOT re-add software L2 prefetch (R5: +640MB FETCH, +1.8ms).
// Pair-sync: relaxed agent-scope atomics + monotonic flags (no acquire/release
// so L2 weight residency survives); writer: data -> __syncthreads (vmcnt
// drain) -> tid0 posts flag; reader: tid0 polls -> barrier -> loads. Flags
// zeroed by k_prep each launch (graph-replay safe).
static constexpr size_t O_EMBW  = 0;         // [2][256 cls][512] emb@Wih0^T + b0 (own half)
static constexpr size_t O_WPT   = 262144;    // [2][256 k][128 c_local]
static constexpr size_t O_WIHT  = 327680;    // [2][3][256 k][512]
static constexpr size_t O_WHHT  = 1114112;   // [2][3][256 k][512]
static constexpr size_t O_BIASC = 1900544;   // [3][256 u][4 g]  bih+bhh (global U)
static constexpr size_t O_XCHG  = 1903616;   // [128 smp][2 half][4 phase][1024] floats
static constexpr size_t O_FLAGS = 2952192;   // 1024 uint32: [smp][4 phase][2 half]
// total 2953216 floats ≈ 11.8 MB

typedef float f2 __attribute__((ext_vector_type(2)));
__device__ __forceinline__ f2 fma2(f2 a, f2 b, f2 c){ return __builtin_elementwise_fma(a,b,c); }
__device__ __forceinline__ float sigf(float x){ return 1.0f/(1.0f + expf(-x)); }

__device__ __forceinline__ void astoref(float* p, float v){
  __hip_atomic_store(p, v, __ATOMIC_RELAXED, __HIP_MEMORY_SCOPE_AGENT);
}
__device__ __forceinline__ float aloadf(const float* p){
  return __hip_atomic_load((float*)p, __ATOMIC_RELAXED, __HIP_MEMORY_SCOPE_AGENT);
}

// ---------------- one-time prep: transposes + combined biases + flag reset ----
__global__ __launch_bounds__(256) void k_prep(
    const float* __restrict__ Wih, const float* __restrict__ Whh,
    const float* __restrict__ Wp,  const float* __restrict__ bih,
    const float* __restrict__ bhh,
    float* __restrict__ wihT, float* __restrict__ whhT,
    float* __restrict__ WpT, float* __restrict__ biasC,
    float* __restrict__ flagsF)
{
  const int NT = 786432;
  const int TOTAL = 2*NT + 65536 + 3072 + 1024;
  int stride = gridDim.x * blockDim.x;
  for (int i = blockIdx.x*blockDim.x + threadIdx.x; i < TOTAL; i += stride){
    if (i < NT){
      int l = i / 262144, r = i % 262144;      // r = row*256 + k
      int row = r >> 8, k = r & 255;
      int g = row >> 8, uu = row & 255;
      int hf = uu >> 7, ul = uu & 127;
      wihT[(size_t)hf*393216 + (size_t)l*131072 + (k<<9) + (ul<<2) + g] = Wih[i];
    } else if (i < 2*NT){
      int j = i - NT;
      int l = j / 262144, r = j % 262144;
      int row = r >> 8, k = r & 255;
      int g = row >> 8, uu = row & 255;
      int hf = uu >> 7, ul = uu & 127;
      whhT[(size_t)hf*393216 + (size_t)l*131072 + (k<<9) + (ul<<2) + g] = Whh[j];
    } else if (i < 2*NT + 65536){
      int j = i - 2*NT; int c = j >> 8, k = j & 255;
      int hf = c >> 7, cl = c & 127;
      WpT[hf*32768 + (k<<7) + cl] = Wp[j];
    } else if (i < 2*NT + 65536 + 3072){
      int j = i - 2*NT - 65536;          // [3][256][4]
      int l = j >> 10; int cg = j & 1023, uu = cg >> 2, g = cg & 3;
      biasC[j] = bih[l*1024 + g*256 + uu] + bhh[l*1024 + g*256 + uu];
    } else {
      flagsF[i - (2*NT + 65536 + 3072)] = 0.0f;   // zero sync flags every launch
    }
  }
}

// ------- one-time: embWc[half][cls][ul*4+g] = emb@Wih0^T + bih0 + bhh0 -------
__global__ __launch_bounds__(256) void k_embW(
    const float* __restrict__ emb, const float* __restrict__ wihTc,
    const float* __restrict__ bih, const float* __restrict__ bhh,
    float* __restrict__ embW)
{
  const int cls = blockIdx.x, uu = threadIdx.x;
  const int hf = uu >> 7, ul = uu & 127;
  const float* er = emb + cls*256;
  const float* W0 = wihTc + (size_t)hf*393216;   // layer 0 of own half
  float a0=0.f,a1=0.f,a2=0.f,a3=0.f;
  for (int k=0;k<256;k++){
    float ev = er[k];
    float4 w = *(const float4*)&W0[(k<<9) + ul*4];
    a0 = fmaf(ev, w.x, a0); a1 = fmaf(ev, w.y, a1);
    a2 = fmaf(ev, w.z, a2); a3 = fmaf(ev, w.w, a3);
  }
  a0 += bih[uu]       + bhh[uu];
  a1 += bih[256+uu]   + bhh[256+uu];
  a2 += bih[512+uu]   + bhh[512+uu];
  a3 += bih[768+uu]   + bhh[768+uu];
  *(float4*)&embW[(size_t)hf*131072 + cls*512 + ul*4] = make_float4(a0,a1,a2,a3);
}

// ---------------- decode: 2 blocks = 1 sample, 512 threads each --------------
__global__
__attribute__((amdgpu_flat_work_group_size(512,512)))
void k_decode(
    const float* __restrict__ x,      // [64][128][256]
    const float* __restrict__ WpT,    // [2][256 k][128]
    const float* __restrict__ wihT,   // [2][3][256 k][512]
    const float* __restrict__ whhT,   // [2][3][256 k][512]
    const float* __restrict__ biasC,  // [3][256 u][4 g]
    const float* __restrict__ embW,   // [2][256 cls][512]
    const float* __restrict__ bp,     // [256]
    float* __restrict__ xchg,         // [128][2][4][1024]
    unsigned* __restrict__ flags,     // [128][4][2]
    float* __restrict__ out)
{
  __shared__ float hS[3*2048];   // h[l][row][unit 0..255] FULL width   24 KB
  __shared__ float cS[1024];     // staged c_old[row][own-unit 0..127]   4 KB
  __shared__ float st[2048];     // state[row][unit] FULL width          8 KB
  __shared__ float jnt[6144];    // logits / reduction slots (512x12)   24 KB
  __shared__ float pfx[8];
  __shared__ float cvS[64]; __shared__ int ciS[64];   // top-8 candidates
  __shared__ float sVal[8]; __shared__ int sPrev[8], sCls[8];
  __shared__ short prevH[512], clsH[512];

  const int tid  = threadIdx.x;
  const int bid  = blockIdx.x;
  const int half = (bid & 7) >> 2;          // 0: XCD 0-3, 1: XCD 4-7 (heuristic)
  const int oh   = half ^ 1;
  const int smp  = ((bid >> 3) << 2) | (bid & 3);   // sample 0..127, bijective
  const int u    = tid & 127;               // local unit / class col
  const int kq   = tid >> 7;                // k-quarter 0..3 (LSTM split-K)
  const int U    = (half << 7) | u;         // global unit / class
  const int or0  = kq*2;                    // owned beam rows (epilogue)
  const int or1  = or0 + 1;
  const int wv   = tid >> 6, lane = tid & 63;

  // own-half contiguous weight bases
  const float* wihB = wihT + (size_t)half*393216;   // [3][256][512]
  const float* whhB = whhT + (size_t)half*393216;
  const float* WpB  = WpT  + half*32768;            // [256][128]
  const float* embB = embW + (size_t)half*131072;   // [256][512]

  float* xbase = xchg + (size_t)smp*8192;
  unsigned* fme = flags + smp*8 + half;     // use fme[p*2]
  unsigned* fpr = flags + smp*8 + oh;

  float creg[3][2];                         // c for owned rows or0/or1, unit u
  const float bpc = bp[U];

  // ---- init: x0 into jnt[2048..2303]; st = x0 broadcast; prefix ----
  if (tid < 64) *(float4*)&jnt[2048 + tid*4] = *(const float4*)&x[(size_t)smp*256 + tid*4];
  if (tid < 8)  pfx[tid] = (tid==0) ? 0.0f : -1e30f;
  __syncthreads();
  *(float4*)&st[tid*4] = *(const float4*)&jnt[2048 + (tid&63)*4];

  // ---- init LSTM from zero state (M=1); per layer: compute own half, exchange
  for (int l=0; l<3; l++){
    if (tid < 128){
      const float* Wg = wihB + (size_t)l*131072;
      float a0=0.f,a1=0.f,a2=0.f,a3=0.f;
      for (int kc=0; kc<256; kc+=4){
        float4 a4 = *(const float4*)&jnt[2048+kc];
        float4 w0 = *(const float4*)&Wg[(size_t)(kc+0)*512 + u*4];
        float4 w1 = *(const float4*)&Wg[(size_t)(kc+1)*512 + u*4];
        float4 w2 = *(const float4*)&Wg[(size_t)(kc+2)*512 + u*4];
        float4 w3 = *(const float4*)&Wg[(size_t)(kc+3)*512 + u*4];
        a0=fmaf(a4.x,w0.x,a0); a0=fmaf(a4.y,w1.x,a0); a0=fmaf(a4.z,w2.x,a0); a0=fmaf(a4.w,w3.x,a0);
        a1=fmaf(a4.x,w0.y,a1); a1=fmaf(a4.y,w1.y,a1); a1=fmaf(a4.z,w2.y,a1); a1=fmaf(a4.w,w3.y,a1);
        a2=fmaf(a4.x,w0.z,a2); a2=fmaf(a4.y,w1.z,a2); a2=fmaf(a4.z,w2.z,a2); a2=fmaf(a4.w,w3.z,a2);
        a3=fmaf(a4.x,w0.w,a3); a3=fmaf(a4.y,w1.w,a3); a3=fmaf(a4.z,w2.w,a3); a3=fmaf(a4.w,w3.w,a3);
      }
      float4 bs = *(const float4*)&biasC[(l*256+U)*4];
      float gi=a0+bs.x, gg=a2+bs.z, go=a3+bs.w;  // c_old=0
      float cn = sigf(gi)*tanhf(gg);
      float hn = sigf(go)*tanhf(cn);
      jnt[tid] = hn; jnt[128+tid] = cn;
    }
    __syncthreads();
    {
      float* xm = xbase + (half*4 + (l+1))*1024;
      float hv = jnt[u], cv = jnt[128+u];
      creg[l][0] = cv; creg[l][1] = cv;
      hS[l*2048 + or0*256 + U] = hv;
      hS[l*2048 + or1*256 + U] = hv;
      astoref(&xm[or0*128 + u], hv);
      astoref(&xm[or1*128 + u], hv);
    }
    __syncthreads();   // drains vmcnt: exchange data at MALL
    if (tid==0){
      __hip_atomic_store(&fme[(l+1)*2], 1u, __ATOMIC_RELAXED, __HIP_MEMORY_SCOPE_AGENT);
      while (__hip_atomic_load(&fpr[(l+1)*2], __ATOMIC_RELAXED, __HIP_MEMORY_SCOPE_AGENT) < 1u)
        __builtin_amdgcn_s_sleep(2);
    }
    __syncthreads();
    {
      const float* xr = xbase + (oh*4 + (l+1))*1024;
      int r = tid>>6, u2 = (tid&63)*2;
      float v0 = aloadf(&xr[r*128+u2]);
      float v1 = aloadf(&xr[r*128+u2+1]);
      hS[l*2048 + r*256 + (oh<<7)+u2]   = v0;
      hS[l*2048 + r*256 + (oh<<7)+u2+1] = v1;
      if (l<2 && r==0){ jnt[2048+(oh<<7)+u2] = v0; jnt[2048+(oh<<7)+u2+1] = v1; }
    }
    if (l<2 && tid<128) jnt[2048 + U] = jnt[tid];   // own half of next input row
    __syncthreads();
  }

  // split-K GEMM: ALL 8 rows x 4 gate-cols of unit u over this thread's 64 k's.
  // 2-stage rolling W prefetch (32 VGPR). acc2: row i -> acc2[i*2]={g_i,g_f},
  // acc2[i*2+1]={g_g,g_o}. W rows are 512 floats (own-half contiguous).
  auto gemm8 = [&](const float* hbaseK, const int* ro, const float* WgK, f2* acc2){
    const float* Wr = WgK + (u<<2);
    float4 wst[2][4];
    #pragma unroll
    for (int s=0; s<2; s++){
      const float* Wn = Wr + (size_t)(s*4)*512;
      wst[s][0]=*(const float4*)&Wn[0];    wst[s][1]=*(const float4*)&Wn[512];
      wst[s][2]=*(const float4*)&Wn[1024]; wst[s][3]=*(const float4*)&Wn[1536];
    }
    auto macblk = [&](const float4 wk[4], const float4 a[8]){
      #pragma unroll
      for (int kk=0;kk<4;kk++){
        f2 wlo = {wk[kk].x, wk[kk].y};
        f2 whi = {wk[kk].z, wk[kk].w};
        const float av4[8] = {
          kk==0?a[0].x:(kk==1?a[0].y:(kk==2?a[0].z:a[0].w)),
          kk==0?a[1].x:(kk==1?a[1].y:(kk==2?a[1].z:a[1].w)),
          kk==0?a[2].x:(kk==1?a[2].y:(kk==2?a[2].z:a[2].w)),
          kk==0?a[3].x:(kk==1?a[3].y:(kk==2?a[3].z:a[3].w)),
          kk==0?a[4].x:(kk==1?a[4].y:(kk==2?a[4].z:a[4].w)),
          kk==0?a[5].x:(kk==1?a[5].y:(kk==2?a[5].z:a[5].w)),
          kk==0?a[6].x:(kk==1?a[6].y:(kk==2?a[6].z:a[6].w)),
          kk==0?a[7].x:(kk==1?a[7].y:(kk==2?a[7].z:a[7].w))};
        #pragma unroll
        for (int i=0;i<8;i++){
          f2 av = {av4[i], av4[i]};
          acc2[i*2+0] = fma2(av, wlo, acc2[i*2+0]);
          acc2[i*2+1] = fma2(av, whi, acc2[i*2+1]);
        }
      }
    };
    #pragma unroll 1
    for (int kc=0; kc<56; kc+=8){             // consume k 0..55, refill to 63
      #pragma unroll
      for (int s=0; s<2; s++){
        const int kcur = kc + s*4;
        const float4 wk[4] = {wst[s][0], wst[s][1], wst[s][2], wst[s][3]};
        const float* Wn = Wr + (size_t)(kcur+8)*512;
        wst[s][0]=*(const float4*)&Wn[0];    wst[s][1]=*(const float4*)&Wn[512];
        wst[s][2]=*(const float4*)&Wn[1024]; wst[s][3]=*(const float4*)&Wn[1536];
        float4 a[8];
        #pragma unroll
        for (int i=0;i<8;i++) a[i] = *(const float4*)&hbaseK[ro[i] + kcur];
        macblk(wk, a);
      }
    }
    #pragma unroll
    for (int s=0; s<2; s++){                  // tail: k=56..63, no refill
      const int kcur = 56 + s*4;
      const float4 wk[4] = {wst[s][0], wst[s][1], wst[s][2], wst[s][3]};
      float4 a[8];
      #pragma unroll
      for (int i=0;i<8;i++) a[i] = *(const float4*)&hbaseK[ro[i] + kcur];
      macblk(wk, a);
    }
  };

  const int kqb = kq << 6;                  // this thread's 64-k base

  // ---------------- 64 decode steps ----------------
  for (int t=0; t<64; t++){
    // ---- phase3 poll: partner h[2] (+ partner half of st for t>0) ----
    if (tid==0){
      unsigned want = (unsigned)(t+1);
      while (__hip_atomic_load(&fpr[3*2], __ATOMIC_RELAXED, __HIP_MEMORY_SCOPE_AGENT) < want)
        __builtin_amdgcn_s_sleep(2);
    }
    __syncthreads();
    {
      const float* xr = xbase + (oh*4 + 3)*1024;
      int r = tid>>6, u2 = (tid&63)*2;
      float v0 = aloadf(&xr[r*128+u2]);
      float v1 = aloadf(&xr[r*128+u2+1]);
      hS[2*2048 + r*256 + (oh<<7)+u2]   = v0;
      hS[2*2048 + r*256 + (oh<<7)+u2+1] = v1;
      if (t > 0){
        f2 xv = *(const f2*)&x[(size_t)t*32768 + smp*256 + (oh<<7)+u2];
        st[r*256 + (oh<<7)+u2]   = v0 + xv.x;
        st[r*256 + (oh<<7)+u2+1] = v1 + xv.y;
      }
    }
    __syncthreads();   // st/hS[2] complete

    // ---- proj: rows rq*2, rq*2+1, own class col u (local, stride 128);
    // full 256-k per thread, 4-stage scalar W prefetch. ----
    {
      const int rq = tid >> 7;                 // 0..3
      const float* A0 = st + (rq*2)*256;
      const float* A1 = st + (rq*2+1)*256;
      const float* Wc = WpB + u;
      f2 q01 = {0.f,0.f};
      float wstp[4][4];
      #pragma unroll
      for (int s=0;s<4;s++){
        #pragma unroll
        for (int q=0;q<4;q++) wstp[s][q] = Wc[(s*4+q)*128];
      }
      #pragma unroll 1
      for (int kc=0; kc<240; kc+=16){
        #pragma unroll
        for (int s=0;s<4;s++){
          const int kcur = kc + s*4;
          float w0=wstp[s][0], w1=wstp[s][1], w2=wstp[s][2], w3=wstp[s][3];
          #pragma unroll
          for (int q=0;q<4;q++) wstp[s][q] = Wc[(kcur+16+q)*128];
          float4 a0 = *(const float4*)&A0[kcur];
          float4 a1 = *(const float4*)&A1[kcur];
          q01 = fma2((f2){a0.x,a1.x}, (f2){w0,w0}, q01);
          q01 = fma2((f2){a0.y,a1.y}, (f2){w1,w1}, q01);
          q01 = fma2((f2){a0.z,a1.z}, (f2){w2,w2}, q01);
          q01 = fma2((f2){a0.w,a1.w}, (f2){w3,w3}, q01);
        }
      }
      #pragma unroll
      for (int s=0;s<4;s++){
        const int kcur = 240 + s*4;
        float w0=wstp[s][0], w1=wstp[s][1], w2=wstp[s][2], w3=wstp[s][3];
        float4 a0 = *(const float4*)&A0[kcur];
        float4 a1 = *(const float4*)&A1[kcur];
        q01 = fma2((f2){a0.x,a1.x}, (f2){w0,w0}, q01);
        q01 = fma2((f2){a0.y,a1.y}, (f2){w1,w1}, q01);
        q01 = fma2((f2){a0.z,a1.z}, (f2){w2,w2}, q01);
        q01 = fma2((f2){a0.w,a1.w}, (f2){w3,w3}, q01);
      }
      float v0 = q01.x + bpc, v1 = q01.y + bpc;
      float* xm = xbase + (half*4 + 0)*1024;
      jnt[(rq*2)*256 + U]   = v0;
      jnt[(rq*2+1)*256 + U] = v1;
      astoref(&xm[(rq*2)*128 + u],   v0);
      astoref(&xm[(rq*2+1)*128 + u], v1);
    }
    __syncthreads();   // jnt own half visible; exchange data at MALL
    if (tid==0){
      __hip_atomic_store(&fme[0], (unsigned)(t+1), __ATOMIC_RELAXED, __HIP_MEMORY_SCOPE_AGENT);
      while (__hip_atomic_load(&fpr[0], __ATOMIC_RELAXED, __HIP_MEMORY_SCOPE_AGENT) < (unsigned)(t+1))
        __builtin_amdgcn_s_sleep(2);
    }
    __syncthreads();
    {
      const float* xr = xbase + (oh*4 + 0)*1024;
      int r = tid>>6, c2 = (tid&63)*2;
      jnt[r*256 + (oh<<7) + c2]   = aloadf(&xr[r*128+c2]);
      jnt[r*256 + (oh<<7) + c2+1] = aloadf(&xr[r*128+c2+1]);
    }
    __syncthreads();

    // ---- log-softmax + prefix: wave wv handles beam-row wv (redundant x2) ----
    {
      const int kb = wv;
      float4 v = *(const float4*)&jnt[kb*256 + lane*4];
      float m = fmaxf(fmaxf(v.x,v.y),fmaxf(v.z,v.w));
      for (int off=32;off;off>>=1) m = fmaxf(m, __shfl_down(m,off));
      m = __shfl(m, 0);
      double s = exp((double)v.x-(double)m)+exp((double)v.y-(double)m)
               + exp((double)v.z-(double)m)+exp((double)v.w-(double)m);
      for (int off=32;off;off>>=1) s += __shfl_down(s,off);
      s = __shfl(s, 0);
      double lse = log(s);
      float pf = pfx[kb];
      float4 o;
      o.x = (float)((double)v.x - (double)m - lse) + pf;
      o.y = (float)((double)v.y - (double)m - lse) + pf;
      o.z = (float)((double)v.z - (double)m - lse) + pf;
      o.w = (float)((double)v.w - (double)m - lse) + pf;
      *(float4*)&jnt[kb*256+lane*4] = o;
    }
    __syncthreads();

    // ---- top-8: per-wave (= per-row) in-wave top-8, then wave-0 merge ----
    {
      float4 v4 = *(const float4*)&jnt[wv*256 + lane*4];
      float e0=v4.x, e1=v4.y, e2=v4.z, e3=v4.w;
      const int ib = wv*256 + lane*4;
      #pragma unroll 1
      for (int r=0;r<8;r++){
        float bv = e0; int bi = ib;
        if (e1>bv){bv=e1;bi=ib+1;}
        if (e2>bv){bv=e2;bi=ib+2;}
        if (e3>bv){bv=e3;bi=ib+3;}
        #pragma unroll
        for (int off=32;off;off>>=1){
          float ov=__shfl_down(bv,off); int oi=__shfl_down(bi,off);
          if (ov>bv||(ov==bv&&oi<bi)){bv=ov;bi=oi;}
        }
        bi=__shfl(bi,0);
        if (lane==0){ cvS[wv*8+r]=bv; ciS[wv*8+r]=bi; }
        if (bi==ib)        e0=-INFINITY;
        else if (bi==ib+1) e1=-INFINITY;
        else if (bi==ib+2) e2=-INFINITY;
        else if (bi==ib+3) e3=-INFINITY;
      }
    }
    __syncthreads();
    if (wv==0){
      float mv = cvS[lane]; int mi = ciS[lane];
      #pragma unroll 1
      for (int r=0;r<8;r++){
        float bv=mv; int bi=mi;
        #pragma unroll
        for (int off=32;off;off>>=1){
          float ov=__shfl_down(bv,off); int oi=__shfl_down(bi,off);
          if (ov>bv||(ov==bv&&oi<bi)){bv=ov;bi=oi;}
        }
        bv=__shfl(bv,0); bi=__shfl(bi,0);
        if (lane==0){ sVal[r]=bv; sPrev[r]=bi>>8; sCls[r]=bi&255; }
        if (mi==bi) mv=-INFINITY;
      }
    }
    __syncthreads();
    if (tid<8){
      pfx[tid] = sVal[tid];
      prevH[t*8+tid] = (short)sPrev[tid];
      clsH[t*8+tid]  = (short)sCls[tid];
    }
    __syncthreads();

    int rog8[8], rod8[8];
    #pragma unroll
    for (int r=0;r<8;r++){ rog8[r] = sPrev[r]*256; rod8[r] = r*256; }
    const int clr0 = sCls[or0], clr1 = sCls[or1];
    const int pv0  = sPrev[or0], pv1 = sPrev[or1];

    // ---- 3 LSTM layers (unit-split across pair, 4-way split-K in block) ----
    #pragma unroll 1
    for (int l=0; l<3; l++){
      cS[or0*128 + u] = creg[l][0];
      cS[or1*128 + u] = creg[l][1];
      __syncthreads();   // cS visible; hS stable; jnt free

      f2 acc2[16];
      #pragma unroll
      for (int i=0;i<16;i++) acc2[i] = (f2){0.f,0.f};
      // recurrent first (operands resident) -> hides the h[l-1] exchange poll
      gemm8(hS + l*2048 + kqb, rog8,
            whhB + (size_t)l*131072 + (size_t)kqb*512, acc2);
      if (l > 0){
        if (tid==0){
          unsigned want = (unsigned)(t+2);
          while (__hip_atomic_load(&fpr[l*2], __ATOMIC_RELAXED, __HIP_MEMORY_SCOPE_AGENT) < want)
            __builtin_amdgcn_s_sleep(2);
        }
        __syncthreads();
        {
          const float* xr = xbase + (oh*4 + l)*1024;
          int r = tid>>6, u2 = (tid&63)*2;
          hS[(l-1)*2048 + r*256 + (oh<<7)+u2]   = aloadf(&xr[r*128+u2]);
          hS[(l-1)*2048 + r*256 + (oh<<7)+u2+1] = aloadf(&xr[r*128+u2+1]);
        }
        __syncthreads();
        gemm8(hS + (l-1)*2048 + kqb, rod8,
              wihB + (size_t)l*131072 + (size_t)kqb*512, acc2);
      }

      // ---- 3-round static XOR-tree reduction (slots: jnt[tid*12], 8 floats) --
      // A1/A2: partner tid^256 (kq^2). kq<2 keeps rows 0-3, kq>=2 keeps 4-7.
      // B: partner tid^128 (kq^1). Final: rows or0=2kq, or1 in G0..G3.
      f2 G0, G1, G2, G3;
      {
        const int dA = (tid ^ 256) * 12;
        const int dB = (tid ^ 128) * 12;
        float4 p0, p1, r0, r1;
        // A1: ship rows {4,5} (kq<2) / {0,1} (kq>=2)
        if (kq < 2){
          p0 = make_float4(acc2[8].x, acc2[8].y, acc2[9].x, acc2[9].y);
          p1 = make_float4(acc2[10].x,acc2[10].y,acc2[11].x,acc2[11].y);
        } else {
          p0 = make_float4(acc2[0].x, acc2[0].y, acc2[1].x, acc2[1].y);
          p1 = make_float4(acc2[2].x, acc2[2].y, acc2[3].x, acc2[3].y);
        }
        *(float4*)&jnt[dA] = p0; *(float4*)&jnt[dA+4] = p1;
        __syncthreads();
        r0 = *(const float4*)&jnt[tid*12];
        r1 = *(const float4*)&jnt[tid*12+4];
        if (kq < 2){
          acc2[0] += (f2){r0.x,r0.y}; acc2[1] += (f2){r0.z,r0.w};
          acc2[2] += (f2){r1.x,r1.y}; acc2[3] += (f2){r1.z,r1.w};
        } else {
          acc2[0] = acc2[8]  + (f2){r0.x,r0.y}; acc2[1] = acc2[9]  + (f2){r0.z,r0.w};
          acc2[2] = acc2[10] + (f2){r1.x,r1.y}; acc2[3] = acc2[11] + (f2){r1.z,r1.w};
        }
        __syncthreads();   // slot reuse
        // A2: ship rows {6,7} (kq<2) / {2,3} (kq>=2)
        if (kq < 2){
          p0 = make_float4(acc2[12].x,acc2[12].y,acc2[13].x,acc2[13].y);
          p1 = make_float4(acc2[14].x,acc2[14].y,acc2[15].x,acc2[15].y);
        } else {
          p0 = make_float4(acc2[4].x, acc2[4].y, acc2[5].x, acc2[5].y);
          p1 = make_float4(acc2[6].x, acc2[6].y, acc2[7].x, acc2[7].y);
        }
        *(float4*)&jnt[dA] = p0; *(float4*)&jnt[dA+4] = p1;
        __syncthreads();
        r0 = *(const float4*)&jnt[tid*12];
        r1 = *(const float4*)&jnt[tid*12+4];
        if (kq < 2){
          acc2[4] += (f2){r0.x,r0.y}; acc2[5] += (f2){r0.z,r0.w};
          acc2[6] += (f2){r1.x,r1.y}; acc2[7] += (f2){r1.z,r1.w};
        } else {
          acc2[4] = acc2[12] + (f2){r0.x,r0.y}; acc2[5] = acc2[13] + (f2){r0.z,r0.w};
          acc2[6] = acc2[14] + (f2){r1.x,r1.y}; acc2[7] = acc2[15] + (f2){r1.z,r1.w};
        }
        __syncthreads();   // slot reuse
        // B: ship the non-owned row pair; keep the owned pair.
        if (kq & 1){
          p0 = make_float4(acc2[0].x, acc2[0].y, acc2[1].x, acc2[1].y);
          p1 = make_float4(acc2[2].x, acc2[2].y, acc2[3].x, acc2[3].y);
        } else {
          p0 = make_float4(acc2[4].x, acc2[4].y, acc2[5].x, acc2[5].y);
          p1 = make_float4(acc2[6].x, acc2[6].y, acc2[7].x, acc2[7].y);
        }
        *(float4*)&jnt[dB] = p0; *(float4*)&jnt[dB+4] = p1;
        __syncthreads();
        r0 = *(const float4*)&jnt[tid*12];
        r1 = *(const float4*)&jnt[tid*12+4];
        f2 k0, k1, k2, k3;
        if (kq & 1){ k0=acc2[4]; k1=acc2[5]; k2=acc2[6]; k3=acc2[7]; }
        else       { k0=acc2[0]; k1=acc2[1]; k2=acc2[2]; k3=acc2[3]; }
        G0 = k0 + (f2){r0.x,r0.y};   // row or0 {i,f}
        G1 = k1 + (f2){r0.z,r0.w};   // row or0 {g,o}
        G2 = k2 + (f2){r1.x,r1.y};   // row or1 {i,f}
        G3 = k3 + (f2){r1.z,r1.w};   // row or1 {g,o}
      }

      // ---- cell epilogue: every thread finalizes its rows or0, or1 ----
      {
        const int tn = (t < 63) ? (t+1) : 63;
        float4 b0, b1;
        if (l==0){
          b0 = *(const float4*)&embB[(size_t)clr0*512 + u*4];
          b1 = *(const float4*)&embB[(size_t)clr1*512 + u*4];
        } else {
          b0 = *(const float4*)&biasC[(l*256+U)*4];
          b1 = b0;
        }
        float co0 = cS[pv0*128 + u], co1 = cS[pv1*128 + u];
        float gi0 = G0.x + b0.x, gf0 = G0.y + b0.y;
        float gg0 = G1.x + b0.z, go0 = G1.y + b0.w;
        float cn0 = sigf(gf0)*co0 + sigf(gi0)*tanhf(gg0);
        float hn0 = sigf(go0)*tanhf(cn0);
        float gi1 = G2.x + b1.x, gf1 = G2.y + b1.y;
        float gg1 = G3.x + b1.z, go1 = G3.y + b1.w;
        float cn1 = sigf(gf1)*co1 + sigf(gi1)*tanhf(gg1);
        float hn1 = sigf(go1)*tanhf(cn1);
        creg[l][0] = cn0; creg[l][1] = cn1;
        hS[l*2048 + or0*256 + U] = hn0;
        hS[l*2048 + or1*256 + U] = hn1;
        if (l == 2){
          float xv = x[(size_t)tn*32768 + smp*256 + U];
          st[or0*256 + U] = hn0 + xv;
          st[or1*256 + U] = hn1 + xv;
        }
        float* xm = xbase + (half*4 + (l+1))*1024;
        astoref(&xm[or0*128 + u], hn0);
        astoref(&xm[or1*128 + u], hn1);
      }
      __syncthreads();   // drains vmcnt: h exchange data at MALL before flag
      if (tid==0)
        __hip_atomic_store(&fme[(l+1)*2], (unsigned)(t+2), __ATOMIC_RELAXED, __HIP_MEMORY_SCOPE_AGENT);
    }
  }

  // ---- backtrace choices + prefix (half 0 only; both halves identical) ----
  if (half==0 && tid < 8){
    int e = tid;
    for (int tt=63; tt>=0; --tt){
      out[(size_t)(smp*8+tid)*64 + tt] = (float)clsH[tt*8+e];
      e = (int)prevH[tt*8+e];
    }
    out[65536 + smp*8 + tid] = pfx[tid];
  }
}

extern "C" void kernel_launch(void* const* d_in, const int* in_sizes, int n_in,
                              void* d_out, int out_size, void* d_ws, size_t ws_size,
                              hipStream_t stream)
{
  const float* x   = (const float*)d_in[0];
  const float* emb = (const float*)d_in[1];
  const float* Wih = (const float*)d_in[2];
  const float* Whh = (const float*)d_in[3];
  const float* bih = (const float*)d_in[4];
  const float* bhh = (const float*)d_in[5];
  const float* Wp  = (const float*)d_in[6];
  const float* bp  = (const float*)d_in[7];
  float* ws = (float*)d_ws;

  float* embW  = ws + O_EMBW;
  float* WpT   = ws + O_WPT;
  float* wihT  = ws + O_WIHT;
  float* whhT  = ws + O_WHHT;
  float* biasC = ws + O_BIASC;
  float* xchg  = ws + O_XCHG;
  unsigned* flags = (unsigned*)(ws + O_FLAGS);

  k_prep<<<256,256,0,stream>>>(Wih,Whh,Wp,bih,bhh,wihT,whhT,WpT,biasC, ws + O_FLAGS);
  k_embW<<<256,256,0,stream>>>(emb, wihT, bih, bhh, embW);
  k_decode<<<256,512,0,stream>>>(x, WpT, wihT, whhT, biasC, embW, bp, xchg, flags, (float*)d_out);
}

// Round 9
// 4155.535 us; speedup vs baseline: 1.5117x; 1.0005x over previous
//
#include <hip/hip_runtime.h>
#include <math.h>

// T=64, B=128, H=256, C=256, K=8, L=3.
// Structure: 2 blocks per sample (unit-half split), 256 blocks, 512 threads.
// Lineage: R8 (passing, 4157us) = gemm8 + XOR-tree + R1 proj + wave top-8 +
// dense per-half weight layouts.
// THIS ROUND: XCD-verified role claim. R8's layout change did NOT drop
// FETCH (1.36GB, predicted 0.4GB) -> per pre-commitment, the bid%8->XCD
// round-robin ASSUMPTION is the suspect: if dispatch is chunked, every XCD
// hosts blocks of BOTH halves -> 6.2MB > 4MB L2 -> thrash (~2.2MB/XCD/step
// = the stubborn ~1.1GB). Fix: each block reads its PHYSICAL XCD via
// s_getreg(HW_REG_XCC_ID=20), prefers half=(xcc&7)>=4, claims (smp,half)
// via device-scope atomic counters with overflow fallback (first-choice
// adds sum to 256 -> at most one half overflows -> final counts exactly
// 128/128 -> every slot claimed once). Correctness independent of XCC_ID
// semantics (pure locality hint). Everything else R8-verbatim.
// DO NOT re-add software L2 prefetch (R5: +640MB FETCH, +1.8ms).
// Pair-sync: relaxed agent-scope atomics + monotonic flags (no acquire/release
// so L2 weight residency survives); writer: data -> __syncthreads (vmcnt
// drain) -> tid0 posts flag; reader: tid0 polls -> barrier -> loads. Flags
// + role counters zeroed by k_prep each launch (graph-replay safe).
static constexpr size_t O_EMBW  = 0;         // [2][256 cls][512] emb@Wih0^T + b0 (own half)
static constexpr size_t O_WPT   = 262144;    // [2][256 k][128 c_local]
static constexpr size_t O_WIHT  = 327680;    // [2][3][256 k][512]
static constexpr size_t O_WHHT  = 1114112;   // [2][3][256 k][512]
static constexpr size_t O_BIASC = 1900544;   // [3][256 u][4 g]  bih+bhh (global U)
static constexpr size_t O_XCHG  = 1903616;   // [128 smp][2 half][4 phase][1024] floats
static constexpr size_t O_FLAGS = 2952192;   // 1024 uint32: [smp][4 phase][2 half]
static constexpr size_t O_CTR   = 2953216;   // 8 uint32: role counters [half]
// total 2953224 floats ≈ 11.8 MB

typedef float f2 __attribute__((ext_vector_type(2)));
__device__ __forceinline__ f2 fma2(f2 a, f2 b, f2 c){ return __builtin_elementwise_fma(a,b,c); }
__device__ __forceinline__ float sigf(float x){ return 1.0f/(1.0f + expf(-x)); }

__device__ __forceinline__ void astoref(float* p, float v){
  __hip_atomic_store(p, v, __ATOMIC_RELAXED, __HIP_MEMORY_SCOPE_AGENT);
}
__device__ __forceinline__ float aloadf(const float* p){
  return __hip_atomic_load((float*)p, __ATOMIC_RELAXED, __HIP_MEMORY_SCOPE_AGENT);
}

// ---------------- one-time prep: transposes + combined biases + flag reset ----
__global__ __launch_bounds__(256) void k_prep(
    const float* __restrict__ Wih, const float* __restrict__ Whh,
    const float* __restrict__ Wp,  const float* __restrict__ bih,
    const float* __restrict__ bhh,
    float* __restrict__ wihT, float* __restrict__ whhT,
    float* __restrict__ WpT, float* __restrict__ biasC,
    float* __restrict__ flagsF)
{
  const int NT = 786432;
  const int TOTAL = 2*NT + 65536 + 3072 + 1032;   // + flags(1024) + ctr(8)
  int stride = gridDim.x * blockDim.x;
  for (int i = blockIdx.x*blockDim.x + threadIdx.x; i < TOTAL; i += stride){
    if (i < NT){
      int l = i / 262144, r = i % 262144;      // r = row*256 + k
      int row = r >> 8, k = r & 255;
      int g = row >> 8, uu = row & 255;
      int hf = uu >> 7, ul = uu & 127;
      wihT[(size_t)hf*393216 + (size_t)l*131072 + (k<<9) + (ul<<2) + g] = Wih[i];
    } else if (i < 2*NT){
      int j = i - NT;
      int l = j / 262144, r = j % 262144;
      int row = r >> 8, k = r & 255;
      int g = row >> 8, uu = row & 255;
      int hf = uu >> 7, ul = uu & 127;
      whhT[(size_t)hf*393216 + (size_t)l*131072 + (k<<9) + (ul<<2) + g] = Whh[j];
    } else if (i < 2*NT + 65536){
      int j = i - 2*NT; int c = j >> 8, k = j & 255;
      int hf = c >> 7, cl = c & 127;
      WpT[hf*32768 + (k<<7) + cl] = Wp[j];
    } else if (i < 2*NT + 65536 + 3072){
      int j = i - 2*NT - 65536;          // [3][256][4]
      int l = j >> 10; int cg = j & 1023, uu = cg >> 2, g = cg & 3;
      biasC[j] = bih[l*1024 + g*256 + uu] + bhh[l*1024 + g*256 + uu];
    } else {
      flagsF[i - (2*NT + 65536 + 3072)] = 0.0f;   // zero flags + role ctrs
    }
  }
}

// ------- one-time: embWc[half][cls][ul*4+g] = emb@Wih0^T + bih0 + bhh0 -------
__global__ __launch_bounds__(256) void k_embW(
    const float* __restrict__ emb, const float* __restrict__ wihTc,
    const float* __restrict__ bih, const float* __restrict__ bhh,
    float* __restrict__ embW)
{
  const int cls = blockIdx.x, uu = threadIdx.x;
  const int hf = uu >> 7, ul = uu & 127;
  const float* er = emb + cls*256;
  const float* W0 = wihTc + (size_t)hf*393216;   // layer 0 of own half
  float a0=0.f,a1=0.f,a2=0.f,a3=0.f;
  for (int k=0;k<256;k++){
    float ev = er[k];
    float4 w = *(const float4*)&W0[(k<<9) + ul*4];
    a0 = fmaf(ev, w.x, a0); a1 = fmaf(ev, w.y, a1);
    a2 = fmaf(ev, w.z, a2); a3 = fmaf(ev, w.w, a3);
  }
  a0 += bih[uu]       + bhh[uu];
  a1 += bih[256+uu]   + bhh[256+uu];
  a2 += bih[512+uu]   + bhh[512+uu];
  a3 += bih[768+uu]   + bhh[768+uu];
  *(float4*)&embW[(size_t)hf*131072 + cls*512 + ul*4] = make_float4(a0,a1,a2,a3);
}

// ---------------- decode: 2 blocks = 1 sample, 512 threads each --------------
__global__
__attribute__((amdgpu_flat_work_group_size(512,512)))
void k_decode(
    const float* __restrict__ x,      // [64][128][256]
    const float* __restrict__ WpT,    // [2][256 k][128]
    const float* __restrict__ wihT,   // [2][3][256 k][512]
    const float* __restrict__ whhT,   // [2][3][256 k][512]
    const float* __restrict__ biasC,  // [3][256 u][4 g]
    const float* __restrict__ embW,   // [2][256 cls][512]
    const float* __restrict__ bp,     // [256]
    float* __restrict__ xchg,         // [128][2][4][1024]
    unsigned* __restrict__ flags,     // [128][4][2]
    unsigned* __restrict__ rctr,      // [2] role counters
    float* __restrict__ out)
{
  __shared__ float hS[3*2048];   // h[l][row][unit 0..255] FULL width   24 KB
  __shared__ float cS[1024];     // staged c_old[row][own-unit 0..127]   4 KB
  __shared__ float st[2048];     // state[row][unit] FULL width          8 KB
  __shared__ float jnt[6144];    // logits / reduction slots (512x12)   24 KB
  __shared__ float pfx[8];
  __shared__ float cvS[64]; __shared__ int ciS[64];   // top-8 candidates
  __shared__ float sVal[8]; __shared__ int sPrev[8], sCls[8];
  __shared__ short prevH[512], clsH[512];
  __shared__ int roleS[2];

  const int tid  = threadIdx.x;

  // ---- XCD-verified role claim: prefer own physical XCD's half ----
  if (tid == 0){
    unsigned xcc;
    asm volatile("s_getreg_b32 %0, hwreg(20, 0, 32)" : "=s"(xcc));  // HW_REG_XCC_ID
    int hp = ((xcc & 7) >= 4) ? 1 : 0;
    unsigned idx = atomicAdd(&rctr[hp], 1u);
    int h = hp;
    if (idx >= 128u){ h = hp ^ 1; idx = atomicAdd(&rctr[h], 1u); }
    roleS[0] = (int)idx; roleS[1] = h;
  }
  __syncthreads();
  const int smp  = roleS[0];                // sample 0..127
  const int half = roleS[1];                // unit/class half
  const int oh   = half ^ 1;
  const int u    = tid & 127;               // local unit / class col
  const int kq   = tid >> 7;                // k-quarter 0..3 (LSTM split-K)
  const int U    = (half << 7) | u;         // global unit / class
  const int or0  = kq*2;                    // owned beam rows (epilogue)
  const int or1  = or0 + 1;
  const int wv   = tid >> 6, lane = tid & 63;

  // own-half contiguous weight bases
  const float* wihB = wihT + (size_t)half*393216;   // [3][256][512]
  const float* whhB = whhT + (size_t)half*393216;
  const float* WpB  = WpT  + half*32768;            // [256][128]
  const float* embB = embW + (size_t)half*131072;   // [256][512]

  float* xbase = xchg + (size_t)smp*8192;
  unsigned* fme = flags + smp*8 + half;     // use fme[p*2]
  unsigned* fpr = flags + smp*8 + oh;

  float creg[3][2];                         // c for owned rows or0/or1, unit u
  const float bpc = bp[U];

  // ---- init: x0 into jnt[2048..2303]; st = x0 broadcast; prefix ----
  if (tid < 64) *(float4*)&jnt[2048 + tid*4] = *(const float4*)&x[(size_t)smp*256 + tid*4];
  if (tid < 8)  pfx[tid] = (tid==0) ? 0.0f : -1e30f;
  __syncthreads();
  *(float4*)&st[tid*4] = *(const float4*)&jnt[2048 + (tid&63)*4];

  // ---- init LSTM from zero state (M=1); per layer: compute own half, exchange
  for (int l=0; l<3; l++){
    if (tid < 128){
      const float* Wg = wihB + (size_t)l*131072;
      float a0=0.f,a1=0.f,a2=0.f,a3=0.f;
      for (int kc=0; kc<256; kc+=4){
        float4 a4 = *(const float4*)&jnt[2048+kc];
        float4 w0 = *(const float4*)&Wg[(size_t)(kc+0)*512 + u*4];
        float4 w1 = *(const float4*)&Wg[(size_t)(kc+1)*512 + u*4];
        float4 w2 = *(const float4*)&Wg[(size_t)(kc+2)*512 + u*4];
        float4 w3 = *(const float4*)&Wg[(size_t)(kc+3)*512 + u*4];
        a0=fmaf(a4.x,w0.x,a0); a0=fmaf(a4.y,w1.x,a0); a0=fmaf(a4.z,w2.x,a0); a0=fmaf(a4.w,w3.x,a0);
        a1=fmaf(a4.x,w0.y,a1); a1=fmaf(a4.y,w1.y,a1); a1=fmaf(a4.z,w2.y,a1); a1=fmaf(a4.w,w3.y,a1);
        a2=fmaf(a4.x,w0.z,a2); a2=fmaf(a4.y,w1.z,a2); a2=fmaf(a4.z,w2.z,a2); a2=fmaf(a4.w,w3.z,a2);
        a3=fmaf(a4.x,w0.w,a3); a3=fmaf(a4.y,w1.w,a3); a3=fmaf(a4.z,w2.w,a3); a3=fmaf(a4.w,w3.w,a3);
      }
      float4 bs = *(const float4*)&biasC[(l*256+U)*4];
      float gi=a0+bs.x, gg=a2+bs.z, go=a3+bs.w;  // c_old=0
      float cn = sigf(gi)*tanhf(gg);
      float hn = sigf(go)*tanhf(cn);
      jnt[tid] = hn; jnt[128+tid] = cn;
    }
    __syncthreads();
    {
      float* xm = xbase + (half*4 + (l+1))*1024;
      float hv = jnt[u], cv = jnt[128+u];
      creg[l][0] = cv; creg[l][1] = cv;
      hS[l*2048 + or0*256 + U] = hv;
      hS[l*2048 + or1*256 + U] = hv;
      astoref(&xm[or0*128 + u], hv);
      astoref(&xm[or1*128 + u], hv);
    }
    __syncthreads();   // drains vmcnt: exchange data at MALL
    if (tid==0){
      __hip_atomic_store(&fme[(l+1)*2], 1u, __ATOMIC_RELAXED, __HIP_MEMORY_SCOPE_AGENT);
      while (__hip_atomic_load(&fpr[(l+1)*2], __ATOMIC_RELAXED, __HIP_MEMORY_SCOPE_AGENT) < 1u)
        __builtin_amdgcn_s_sleep(2);
    }
    __syncthreads();
    {
      const float* xr = xbase + (oh*4 + (l+1))*1024;
      int r = tid>>6, u2 = (tid&63)*2;
      float v0 = aloadf(&xr[r*128+u2]);
      float v1 = aloadf(&xr[r*128+u2+1]);
      hS[l*2048 + r*256 + (oh<<7)+u2]   = v0;
      hS[l*2048 + r*256 + (oh<<7)+u2+1] = v1;
      if (l<2 && r==0){ jnt[2048+(oh<<7)+u2] = v0; jnt[2048+(oh<<7)+u2+1] = v1; }
    }
    if (l<2 && tid<128) jnt[2048 + U] = jnt[tid];   // own half of next input row
    __syncthreads();
  }

  // split-K GEMM: ALL 8 rows x 4 gate-cols of unit u over this thread's 64 k's.
  // 2-stage rolling W prefetch (32 VGPR). acc2: row i -> acc2[i*2]={g_i,g_f},
  // acc2[i*2+1]={g_g,g_o}. W rows are 512 floats (own-half contiguous).
  auto gemm8 = [&](const float* hbaseK, const int* ro, const float* WgK, f2* acc2){
    const float* Wr = WgK + (u<<2);
    float4 wst[2][4];
    #pragma unroll
    for (int s=0; s<2; s++){
      const float* Wn = Wr + (size_t)(s*4)*512;
      wst[s][0]=*(const float4*)&Wn[0];    wst[s][1]=*(const float4*)&Wn[512];
      wst[s][2]=*(const float4*)&Wn[1024]; wst[s][3]=*(const float4*)&Wn[1536];
    }
    auto macblk = [&](const float4 wk[4], const float4 a[8]){
      #pragma unroll
      for (int kk=0;kk<4;kk++){
        f2 wlo = {wk[kk].x, wk[kk].y};
        f2 whi = {wk[kk].z, wk[kk].w};
        const float av4[8] = {
          kk==0?a[0].x:(kk==1?a[0].y:(kk==2?a[0].z:a[0].w)),
          kk==0?a[1].x:(kk==1?a[1].y:(kk==2?a[1].z:a[1].w)),
          kk==0?a[2].x:(kk==1?a[2].y:(kk==2?a[2].z:a[2].w)),
          kk==0?a[3].x:(kk==1?a[3].y:(kk==2?a[3].z:a[3].w)),
          kk==0?a[4].x:(kk==1?a[4].y:(kk==2?a[4].z:a[4].w)),
          kk==0?a[5].x:(kk==1?a[5].y:(kk==2?a[5].z:a[5].w)),
          kk==0?a[6].x:(kk==1?a[6].y:(kk==2?a[6].z:a[6].w)),
          kk==0?a[7].x:(kk==1?a[7].y:(kk==2?a[7].z:a[7].w))};
        #pragma unroll
        for (int i=0;i<8;i++){
          f2 av = {av4[i], av4[i]};
          acc2[i*2+0] = fma2(av, wlo, acc2[i*2+0]);
          acc2[i*2+1] = fma2(av, whi, acc2[i*2+1]);
        }
      }
    };
    #pragma unroll 1
    for (int kc=0; kc<56; kc+=8){             // consume k 0..55, refill to 63
      #pragma unroll
      for (int s=0; s<2; s++){
        const int kcur = kc + s*4;
        const float4 wk[4] = {wst[s][0], wst[s][1], wst[s][2], wst[s][3]};
        const float* Wn = Wr + (size_t)(kcur+8)*512;
        wst[s][0]=*(const float4*)&Wn[0];    wst[s][1]=*(const float4*)&Wn[512];
        wst[s][2]=*(const float4*)&Wn[1024]; wst[s][3]=*(const float4*)&Wn[1536];
        float4 a[8];
        #pragma unroll
        for (int i=0;i<8;i++) a[i] = *(const float4*)&hbaseK[ro[i] + kcur];
        macblk(wk, a);
      }
    }
    #pragma unroll
    for (int s=0; s<2; s++){                  // tail: k=56..63, no refill
      const int kcur = 56 + s*4;
      const float4 wk[4] = {wst[s][0], wst[s][1], wst[s][2], wst[s][3]};
      float4 a[8];
      #pragma unroll
      for (int i=0;i<8;i++) a[i] = *(const float4*)&hbaseK[ro[i] + kcur];
      macblk(wk, a);
    }
  };

  const int kqb = kq << 6;                  // this thread's 64-k base

  // ---------------- 64 decode steps ----------------
  for (int t=0; t<64; t++){
    // ---- phase3 poll: partner h[2] (+ partner half of st for t>0) ----
    if (tid==0){
      unsigned want = (unsigned)(t+1);
      while (__hip_atomic_load(&fpr[3*2], __ATOMIC_RELAXED, __HIP_MEMORY_SCOPE_AGENT) < want)
        __builtin_amdgcn_s_sleep(2);
    }
    __syncthreads();
    {
      const float* xr = xbase + (oh*4 + 3)*1024;
      int r = tid>>6, u2 = (tid&63)*2;
      float v0 = aloadf(&xr[r*128+u2]);
      float v1 = aloadf(&xr[r*128+u2+1]);
      hS[2*2048 + r*256 + (oh<<7)+u2]   = v0;
      hS[2*2048 + r*256 + (oh<<7)+u2+1] = v1;
      if (t > 0){
        f2 xv = *(const f2*)&x[(size_t)t*32768 + smp*256 + (oh<<7)+u2];
        st[r*256 + (oh<<7)+u2]   = v0 + xv.x;
        st[r*256 + (oh<<7)+u2+1] = v1 + xv.y;
      }
    }
    __syncthreads();   // st/hS[2] complete

    // ---- proj: rows rq*2, rq*2+1, own class col u (local, stride 128);
    // full 256-k per thread, 4-stage scalar W prefetch. ----
    {
      const int rq = tid >> 7;                 // 0..3
      const float* A0 = st + (rq*2)*256;
      const float* A1 = st + (rq*2+1)*256;
      const float* Wc = WpB + u;
      f2 q01 = {0.f,0.f};
      float wstp[4][4];
      #pragma unroll
      for (int s=0;s<4;s++){
        #pragma unroll
        for (int q=0;q<4;q++) wstp[s][q] = Wc[(s*4+q)*128];
      }
      #pragma unroll 1
      for (int kc=0; kc<240; kc+=16){
        #pragma unroll
        for (int s=0;s<4;s++){
          const int kcur = kc + s*4;
          float w0=wstp[s][0], w1=wstp[s][1], w2=wstp[s][2], w3=wstp[s][3];
          #pragma unroll
          for (int q=0;q<4;q++) wstp[s][q] = Wc[(kcur+16+q)*128];
          float4 a0 = *(const float4*)&A0[kcur];
          float4 a1 = *(const float4*)&A1[kcur];
          q01 = fma2((f2){a0.x,a1.x}, (f2){w0,w0}, q01);
          q01 = fma2((f2){a0.y,a1.y}, (f2){w1,w1}, q01);
          q01 = fma2((f2){a0.z,a1.z}, (f2){w2,w2}, q01);
          q01 = fma2((f2){a0.w,a1.w}, (f2){w3,w3}, q01);
        }
      }
      #pragma unroll
      for (int s=0;s<4;s++){
        const int kcur = 240 + s*4;
        float w0=wstp[s][0], w1=wstp[s][1], w2=wstp[s][2], w3=wstp[s][3];
        float4 a0 = *(const float4*)&A0[kcur];
        float4 a1 = *(const float4*)&A1[kcur];
        q01 = fma2((f2){a0.x,a1.x}, (f2){w0,w0}, q01);
        q01 = fma2((f2){a0.y,a1.y}, (f2){w1,w1}, q01);
        q01 = fma2((f2){a0.z,a1.z}, (f2){w2,w2}, q01);
        q01 = fma2((f2){a0.w,a1.w}, (f2){w3,w3}, q01);
      }
      float v0 = q01.x + bpc, v1 = q01.y + bpc;
      float* xm = xbase + (half*4 + 0)*1024;
      jnt[(rq*2)*256 + U]   = v0;
      jnt[(rq*2+1)*256 + U] = v1;
      astoref(&xm[(rq*2)*128 + u],   v0);
      astoref(&xm[(rq*2+1)*128 + u], v1);
    }
    __syncthreads();   // jnt own half visible; exchange data at MALL
    if (tid==0){
      __hip_atomic_store(&fme[0], (unsigned)(t+1), __ATOMIC_RELAXED, __HIP_MEMORY_SCOPE_AGENT);
      while (__hip_atomic_load(&fpr[0], __ATOMIC_RELAXED, __HIP_MEMORY_SCOPE_AGENT) < (unsigned)(t+1))
        __builtin_amdgcn_s_sleep(2);
    }
    __syncthreads();
    {
      const float* xr = xbase + (oh*4 + 0)*1024;
      int r = tid>>6, c2 = (tid&63)*2;
      jnt[r*256 + (oh<<7) + c2]   = aloadf(&xr[r*128+c2]);
      jnt[r*256 + (oh<<7) + c2+1] = aloadf(&xr[r*128+c2+1]);
    }
    __syncthreads();

    // ---- log-softmax + prefix: wave wv handles beam-row wv (redundant x2) ----
    {
      const int kb = wv;
      float4 v = *(const float4*)&jnt[kb*256 + lane*4];
      float m = fmaxf(fmaxf(v.x,v.y),fmaxf(v.z,v.w));
      for (int off=32;off;off>>=1) m = fmaxf(m, __shfl_down(m,off));
      m = __shfl(m, 0);
      double s = exp((double)v.x-(double)m)+exp((double)v.y-(double)m)
               + exp((double)v.z-(double)m)+exp((double)v.w-(double)m);
      for (int off=32;off;off>>=1) s += __shfl_down(s,off);
      s = __shfl(s, 0);
      double lse = log(s);
      float pf = pfx[kb];
      float4 o;
      o.x = (float)((double)v.x - (double)m - lse) + pf;
      o.y = (float)((double)v.y - (double)m - lse) + pf;
      o.z = (float)((double)v.z - (double)m - lse) + pf;
      o.w = (float)((double)v.w - (double)m - lse) + pf;
      *(float4*)&jnt[kb*256+lane*4] = o;
    }
    __syncthreads();

    // ---- top-8: per-wave (= per-row) in-wave top-8, then wave-0 merge ----
    {
      float4 v4 = *(const float4*)&jnt[wv*256 + lane*4];
      float e0=v4.x, e1=v4.y, e2=v4.z, e3=v4.w;
      const int ib = wv*256 + lane*4;
      #pragma unroll 1
      for (int r=0;r<8;r++){
        float bv = e0; int bi = ib;
        if (e1>bv){bv=e1;bi=ib+1;}
        if (e2>bv){bv=e2;bi=ib+2;}
        if (e3>bv){bv=e3;bi=ib+3;}
        #pragma unroll
        for (int off=32;off;off>>=1){
          float ov=__shfl_down(bv,off); int oi=__shfl_down(bi,off);
          if (ov>bv||(ov==bv&&oi<bi)){bv=ov;bi=oi;}
        }
        bi=__shfl(bi,0);
        if (lane==0){ cvS[wv*8+r]=bv; ciS[wv*8+r]=bi; }
        if (bi==ib)        e0=-INFINITY;
        else if (bi==ib+1) e1=-INFINITY;
        else if (bi==ib+2) e2=-INFINITY;
        else if (bi==ib+3) e3=-INFINITY;
      }
    }
    __syncthreads();
    if (wv==0){
      float mv = cvS[lane]; int mi = ciS[lane];
      #pragma unroll 1
      for (int r=0;r<8;r++){
        float bv=mv; int bi=mi;
        #pragma unroll
        for (int off=32;off;off>>=1){
          float ov=__shfl_down(bv,off); int oi=__shfl_down(bi,off);
          if (ov>bv||(ov==bv&&oi<bi)){bv=ov;bi=oi;}
        }
        bv=__shfl(bv,0); bi=__shfl(bi,0);
        if (lane==0){ sVal[r]=bv; sPrev[r]=bi>>8; sCls[r]=bi&255; }
        if (mi==bi) mv=-INFINITY;
      }
    }
    __syncthreads();
    if (tid<8){
      pfx[tid] = sVal[tid];
      prevH[t*8+tid] = (short)sPrev[tid];
      clsH[t*8+tid]  = (short)sCls[tid];
    }
    __syncthreads();

    int rog8[8], rod8[8];
    #pragma unroll
    for (int r=0;r<8;r++){ rog8[r] = sPrev[r]*256; rod8[r] = r*256; }
    const int clr0 = sCls[or0], clr1 = sCls[or1];
    const int pv0  = sPrev[or0], pv1 = sPrev[or1];

    // ---- 3 LSTM layers (unit-split across pair, 4-way split-K in block) ----
    #pragma unroll 1
    for (int l=0; l<3; l++){
      cS[or0*128 + u] = creg[l][0];
      cS[or1*128 + u] = creg[l][1];
      __syncthreads();   // cS visible; hS stable; jnt free

      f2 acc2[16];
      #pragma unroll
      for (int i=0;i<16;i++) acc2[i] = (f2){0.f,0.f};
      // recurrent first (operands resident) -> hides the h[l-1] exchange poll
      gemm8(hS + l*2048 + kqb, rog8,
            whhB + (size_t)l*131072 + (size_t)kqb*512, acc2);
      if (l > 0){
        if (tid==0){
          unsigned want = (unsigned)(t+2);
          while (__hip_atomic_load(&fpr[l*2], __ATOMIC_RELAXED, __HIP_MEMORY_SCOPE_AGENT) < want)
            __builtin_amdgcn_s_sleep(2);
        }
        __syncthreads();
        {
          const float* xr = xbase + (oh*4 + l)*1024;
          int r = tid>>6, u2 = (tid&63)*2;
          hS[(l-1)*2048 + r*256 + (oh<<7)+u2]   = aloadf(&xr[r*128+u2]);
          hS[(l-1)*2048 + r*256 + (oh<<7)+u2+1] = aloadf(&xr[r*128+u2+1]);
        }
        __syncthreads();
        gemm8(hS + (l-1)*2048 + kqb, rod8,
              wihB + (size_t)l*131072 + (size_t)kqb*512, acc2);
      }

      // ---- 3-round static XOR-tree reduction (slots: jnt[tid*12], 8 floats) --
      // A1/A2: partner tid^256 (kq^2). kq<2 keeps rows 0-3, kq>=2 keeps 4-7.
      // B: partner tid^128 (kq^1). Final: rows or0=2kq, or1 in G0..G3.
      f2 G0, G1, G2, G3;
      {
        const int dA = (tid ^ 256) * 12;
        const int dB = (tid ^ 128) * 12;
        float4 p0, p1, r0, r1;
        // A1: ship rows {4,5} (kq<2) / {0,1} (kq>=2)
        if (kq < 2){
          p0 = make_float4(acc2[8].x, acc2[8].y, acc2[9].x, acc2[9].y);
          p1 = make_float4(acc2[10].x,acc2[10].y,acc2[11].x,acc2[11].y);
        } else {
          p0 = make_float4(acc2[0].x, acc2[0].y, acc2[1].x, acc2[1].y);
          p1 = make_float4(acc2[2].x, acc2[2].y, acc2[3].x, acc2[3].y);
        }
        *(float4*)&jnt[dA] = p0; *(float4*)&jnt[dA+4] = p1;
        __syncthreads();
        r0 = *(const float4*)&jnt[tid*12];
        r1 = *(const float4*)&jnt[tid*12+4];
        if (kq < 2){
          acc2[0] += (f2){r0.x,r0.y}; acc2[1] += (f2){r0.z,r0.w};
          acc2[2] += (f2){r1.x,r1.y}; acc2[3] += (f2){r1.z,r1.w};
        } else {
          acc2[0] = acc2[8]  + (f2){r0.x,r0.y}; acc2[1] = acc2[9]  + (f2){r0.z,r0.w};
          acc2[2] = acc2[10] + (f2){r1.x,r1.y}; acc2[3] = acc2[11] + (f2){r1.z,r1.w};
        }
        __syncthreads();   // slot reuse
        // A2: ship rows {6,7} (kq<2) / {2,3} (kq>=2)
        if (kq < 2){
          p0 = make_float4(acc2[12].x,acc2[12].y,acc2[13].x,acc2[13].y);
          p1 = make_float4(acc2[14].x,acc2[14].y,acc2[15].x,acc2[15].y);
        } else {
          p0 = make_float4(acc2[4].x, acc2[4].y, acc2[5].x, acc2[5].y);
          p1 = make_float4(acc2[6].x, acc2[6].y, acc2[7].x, acc2[7].y);
        }
        *(float4*)&jnt[dA] = p0; *(float4*)&jnt[dA+4] = p1;
        __syncthreads();
        r0 = *(const float4*)&jnt[tid*12];
        r1 = *(const float4*)&jnt[tid*12+4];
        if (kq < 2){
          acc2[4] += (f2){r0.x,r0.y}; acc2[5] += (f2){r0.z,r0.w};
          acc2[6] += (f2){r1.x,r1.y}; acc2[7] += (f2){r1.z,r1.w};
        } else {
          acc2[4] = acc2[12] + (f2){r0.x,r0.y}; acc2[5] = acc2[13] + (f2){r0.z,r0.w};
          acc2[6] = acc2[14] + (f2){r1.x,r1.y}; acc2[7] = acc2[15] + (f2){r1.z,r1.w};
        }
        __syncthreads();   // slot reuse
        // B: ship the non-owned row pair; keep the owned pair.
        if (kq & 1){
          p0 = make_float4(acc2[0].x, acc2[0].y, acc2[1].x, acc2[1].y);
          p1 = make_float4(acc2[2].x, acc2[2].y, acc2[3].x, acc2[3].y);
        } else {
          p0 = make_float4(acc2[4].x, acc2[4].y, acc2[5].x, acc2[5].y);
          p1 = make_float4(acc2[6].x, acc2[6].y, acc2[7].x, acc2[7].y);
        }
        *(float4*)&jnt[dB] = p0; *(float4*)&jnt[dB+4] = p1;
        __syncthreads();
        r0 = *(const float4*)&jnt[tid*12];
        r1 = *(const float4*)&jnt[tid*12+4];
        f2 k0, k1, k2, k3;
        if (kq & 1){ k0=acc2[4]; k1=acc2[5]; k2=acc2[6]; k3=acc2[7]; }
        else       { k0=acc2[0]; k1=acc2[1]; k2=acc2[2]; k3=acc2[3]; }
        G0 = k0 + (f2){r0.x,r0.y};   // row or0 {i,f}
        G1 = k1 + (f2){r0.z,r0.w};   // row or0 {g,o}
        G2 = k2 + (f2){r1.x,r1.y};   // row or1 {i,f}
        G3 = k3 + (f2){r1.z,r1.w};   // row or1 {g,o}
      }

      // ---- cell epilogue: every thread finalizes its rows or0, or1 ----
      {
        const int tn = (t < 63) ? (t+1) : 63;
        float4 b0, b1;
        if (l==0){
          b0 = *(const float4*)&embB[(size_t)clr0*512 + u*4];
          b1 = *(const float4*)&embB[(size_t)clr1*512 + u*4];
        } else {
          b0 = *(const float4*)&biasC[(l*256+U)*4];
          b1 = b0;
        }
        float co0 = cS[pv0*128 + u], co1 = cS[pv1*128 + u];
        float gi0 = G0.x + b0.x, gf0 = G0.y + b0.y;
        float gg0 = G1.x + b0.z, go0 = G1.y + b0.w;
        float cn0 = sigf(gf0)*co0 + sigf(gi0)*tanhf(gg0);
        float hn0 = sigf(go0)*tanhf(cn0);
        float gi1 = G2.x + b1.x, gf1 = G2.y + b1.y;
        float gg1 = G3.x + b1.z, go1 = G3.y + b1.w;
        float cn1 = sigf(gf1)*co1 + sigf(gi1)*tanhf(gg1);
        float hn1 = sigf(go1)*tanhf(cn1);
        creg[l][0] = cn0; creg[l][1] = cn1;
        hS[l*2048 + or0*256 + U] = hn0;
        hS[l*2048 + or1*256 + U] = hn1;
        if (l == 2){
          float xv = x[(size_t)tn*32768 + smp*256 + U];
          st[or0*256 + U] = hn0 + xv;
          st[or1*256 + U] = hn1 + xv;
        }
        float* xm = xbase + (half*4 + (l+1))*1024;
        astoref(&xm[or0*128 + u], hn0);
        astoref(&xm[or1*128 + u], hn1);
      }
      __syncthreads();   // drains vmcnt: h exchange data at MALL before flag
      if (tid==0)
        __hip_atomic_store(&fme[(l+1)*2], (unsigned)(t+2), __ATOMIC_RELAXED, __HIP_MEMORY_SCOPE_AGENT);
    }
  }

  // ---- backtrace choices + prefix (half 0 only; both halves identical) ----
  if (half==0 && tid < 8){
    int e = tid;
    for (int tt=63; tt>=0; --tt){
      out[(size_t)(smp*8+tid)*64 + tt] = (float)clsH[tt*8+e];
      e = (int)prevH[tt*8+e];
    }
    out[65536 + smp*8 + tid] = pfx[tid];
  }
}

extern "C" void kernel_launch(void* const* d_in, const int* in_sizes, int n_in,
                              void* d_out, int out_size, void* d_ws, size_t ws_size,
                              hipStream_t stream)
{
  const float* x   = (const float*)d_in[0];
  const float* emb = (const float*)d_in[1];
  const float* Wih = (const float*)d_in[2];
  const float* Whh = (const float*)d_in[3];
  const float* bih = (const float*)d_in[4];
  const float* bhh = (const float*)d_in[5];
  const float* Wp  = (const float*)d_in[6];
  const float* bp  = (const float*)d_in[7];
  float* ws = (float*)d_ws;

  float* embW  = ws + O_EMBW;
  float* WpT   = ws + O_WPT;
  float* wihT  = ws + O_WIHT;
  float* whhT  = ws + O_WHHT;
  float* biasC = ws + O_BIASC;
  float* xchg  = ws + O_XCHG;
  unsigned* flags = (unsigned*)(ws + O_FLAGS);
  unsigned* rctr  = (unsigned*)(ws + O_CTR);

  k_prep<<<256,256,0,stream>>>(Wih,Whh,Wp,bih,bhh,wihT,whhT,WpT,biasC, ws + O_FLAGS);
  k_embW<<<256,256,0,stream>>>(emb, wihT, bih, bhh, embW);
  k_decode<<<256,512,0,stream>>>(x, WpT, wihT, whhT, biasC, embW, bp, xchg, flags, rctr, (float*)d_out);
}